// Round 8
// baseline (1698.849 us; speedup 1.0000x reference)
//
#include <hip/hip_runtime.h>
#include <hip/hip_bf16.h>
#include <math.h>

#define B_ 2048
#define L_ 32
#define V_ 1024
#define E_ 256
#define H_ 512
#define DEC_T_ 7
#define NA_ (B_ * H_)

typedef unsigned short u16;
typedef unsigned int u32;
using bf16x8 = __attribute__((ext_vector_type(8))) short;
using f32x4  = __attribute__((ext_vector_type(4))) float;

#define WAITVM(n) asm volatile("s_waitcnt vmcnt(" #n ")" ::: "memory")
#define SCHED0()  __builtin_amdgcn_sched_barrier(0)

__device__ __forceinline__ u16 f2b(float f) {
  union { float f; u32 i; } x; x.f = f;
  u32 r = x.i + 0x7FFFu + ((x.i >> 16) & 1u);
  return (u16)(r >> 16);
}
__device__ __forceinline__ float b2f(u16 u) {
  union { u32 i; float f; } x; x.i = ((u32)u) << 16; return x.f;
}
__device__ __forceinline__ float sigm(float x) { return 1.f / (1.f + __expf(-x)); }
__device__ __forceinline__ float tanhfast(float x) {
  const float xx = fminf(fmaxf(x, -15.f), 15.f);
  const float e = __expf(2.f * xx);
  return (e - 1.f) / (e + 1.f);
}

// async global->LDS, 16B per lane. dest = wave-uniform base + lane*16.
__device__ __forceinline__ void gl_lds16(const void* g, void* l) {
  __builtin_amdgcn_global_load_lds((const __attribute__((address_space(1))) u32*)g,
                                   (__attribute__((address_space(3))) u32*)l, 16, 0, 0);
}
// coherent variant (SC0): bypass per-CU L1 (h written by other blocks, same XCD)
__device__ __forceinline__ void gl_lds16c(const void* g, void* l) {
  __builtin_amdgcn_global_load_lds((const __attribute__((address_space(1))) u32*)g,
                                   (__attribute__((address_space(3))) u32*)l, 16, 0, 1);
}

// ---------------------------------------------------------------------------
// Per-XCD monotonic barrier (verified R5/R7). No device fence -> no L2 flush.
// __syncthreads drains vmcnt (h stores in L2) before signaling.
// ---------------------------------------------------------------------------
__device__ __forceinline__ void gbar_mono(unsigned* cnt, unsigned target) {
  __syncthreads();
  if (threadIdx.x == 0) {
    __hip_atomic_fetch_add(cnt, 1u, __ATOMIC_RELAXED, __HIP_MEMORY_SCOPE_AGENT);
    for (int it = 0; it < (1 << 20); ++it) {
      if (__hip_atomic_load(cnt, __ATOMIC_RELAXED, __HIP_MEMORY_SCOPE_AGENT) >= target) break;
      __builtin_amdgcn_s_sleep(2);
    }
  }
  asm volatile("" ::: "memory");
  __syncthreads();
}

// ---------------------------------------------------------------------------
// R8: 256x256 tiles (j x m), 512 threads / 8 waves (wj 2 x wm 4), quad-buffer
// counted-vmcnt K-loop. Rationale (R7 post-mortem): 128^2 tiles made the
// encoder L2-BW-bound (~198 MB L2 reads/step = each W line read by 16
// m-blocks, each h line by 16 j-blocks); schedule changes were neutral.
// 256^2 halves per-step L2 traffic (8 readers instead of 16 each way).
// Per kt: vmcnt(8) -> s_barrier -> stage(kt+3) -> ds_read buf[kt&3] -> 32 MFMA.
// vmcnt exact: 4 loads/wave/stage. Tail peeled vm(8)/vm(4)/vm(0).
// Tiles [256 rows][32 bf16], 16B chunks XOR-swizzled both sides (the swizzle
// lane formulas are invariant under the new decomposition; re-derived).
// LDS 128 KB (4 x 32 KB buffers), 1 block/CU.
// ---------------------------------------------------------------------------

// Persistent bidirectional encoder: 32 LSTM steps, ONE launch, 128 blocks.
// XCD x: dir = x>>2, m-blocks {2(x&3), 2(x&3)+1}, all 8 j-blocks -> h exchange
// intra-XCD; barrier group = 16 blocks. Cell state in registers.
__launch_bounds__(512, 2)
__global__ void enc_persist_k(const int* __restrict__ feat, const u16* __restrict__ emb,
                              const u16* __restrict__ Wf, const u16* __restrict__ Wbk,
                              const float* __restrict__ bsf, const float* __restrict__ bsb,
                              u16* hfa, u16* hfb, u16* hba, u16* hbb,
                              unsigned* bar) {
  __shared__ u16 sh[4 * 16384];   // 128 KB: 4 x (W 16KB | A 16KB)
  const int tid = threadIdx.x;
  const int lane = tid & 63, wave = tid >> 6;          // 8 waves
  const int wj = wave >> 2, wm = wave & 3;             // 2 x 4
  const int bid = blockIdx.x;
  const int xcd = bid & 7;
  const int wi = bid >> 3;                             // 0..15 within XCD
  const int dir = xcd >> 2;
  const int j0 = (wi & 7) * 256;
  const int m0 = ((xcd & 3) * 2 + (wi >> 3)) * 256;
  const u16* W = dir ? Wbk : Wf;
  const float* bsum = dir ? bsb : bsf;
  u16* hA = dir ? hba : hfa;
  u16* hB = dir ? hbb : hfb;
  unsigned* cnt = bar + xcd * 64;

  const int lr = lane & 15;
  const int swk = ((lane >> 4) ^ ((lane >> 1) & 3)) * 8;   // swizzled read chunk
  const int srow = wave * 32 + (lane >> 2);                // rows srow, srow+16
  const int csrc = ((lane & 3) ^ ((lane >> 3) & 3)) * 8;   // swizzled src chunk
  const u16* wsrc0 = W + (j0 + srow) * (E_ + H_) + csrc;
  const u16* wsrc1 = wsrc0 + 16 * (E_ + H_);
  u16* hlds = sh;                                          // stride 72; overlays buf0..buf1[:4KB]
  const int frow0 = (m0 + srow) * L_;
  const int frow1 = (m0 + srow + 16) * L_;
  const int jb_base = j0 + wj * 128 + (lane >> 4) * 4;
  const int n0 = j0 >> 2;                                  // block's 64-wide n range

  float creg[8][4] = {};                                   // cell state, in regs

  for (int s = 0; s < L_; ++s) {
    const int tc = dir ? (L_ - 1 - s) : s;
    const int t0 = feat[frow0 + tc], t1 = feat[frow1 + tc];
    const u16* e0 = emb + t0 * E_ + csrc;
    const u16* e1 = emb + t1 * E_ + csrc;
    const u16* hin = (s & 1) ? hB : hA;
    u16* hout = (s & 1) ? hA : hB;
    const u16* h0 = hin + (m0 + srow) * H_ + csrc - E_;    // valid for k0 >= E_
    const u16* h1 = h0 + 16 * H_;

    if (s) gbar_mono(cnt, 16u * (unsigned)s);              // h(s-1) visible

    auto stage = [&](int kt) {
      const int b = kt & 3;
      const int k0 = kt << 5;
      u16* wd = sh + b * 16384 + wave * 1024;
      u16* ad = sh + b * 16384 + 8192 + wave * 1024;
      gl_lds16(wsrc0 + k0, wd);
      gl_lds16(wsrc1 + k0, wd + 512);
      if (k0 < E_) { gl_lds16(e0 + k0, ad);  gl_lds16(e1 + k0, ad + 512); }
      else         { gl_lds16c(h0 + k0, ad); gl_lds16c(h1 + k0, ad + 512); }
    };

    f32x4 acc[8][4] = {};
    auto compute = [&](int kt) {
      const u16* Wb2 = sh + (kt & 3) * 16384;
      const u16* Ab2 = Wb2 + 8192;
      bf16x8 af[8], bb[4];
#pragma unroll
      for (int t = 0; t < 8; ++t)
        af[t] = *(const bf16x8*)(Wb2 + (wj * 128 + t * 16 + lr) * 32 + swk);
#pragma unroll
      for (int t = 0; t < 4; ++t)
        bb[t] = *(const bf16x8*)(Ab2 + (wm * 64 + t * 16 + lr) * 32 + swk);
#pragma unroll
      for (int i = 0; i < 8; ++i)
#pragma unroll
        for (int j = 0; j < 4; ++j)
          acc[i][j] = __builtin_amdgcn_mfma_f32_16x16x32_bf16(af[i], bb[j], acc[i][j], 0, 0, 0);
    };

    stage(0); stage(1); stage(2);                          // prologue, 12 loads
    for (int kt = 0; kt <= 24 - 4; ++kt) {                 // NT=24
      WAITVM(8); SCHED0();
      __builtin_amdgcn_s_barrier(); SCHED0();
      stage(kt + 3);
      compute(kt);
    }
    WAITVM(8); SCHED0(); __builtin_amdgcn_s_barrier(); SCHED0(); compute(21);
    WAITVM(4); SCHED0(); __builtin_amdgcn_s_barrier(); SCHED0(); compute(22);
    WAITVM(0); SCHED0(); __builtin_amdgcn_s_barrier(); SCHED0(); compute(23);
    // last reads hit buf3 (96..128KB); hlds occupies 0..36KB -> no collision.
    // buf1 (hlds spill region) last read at compute(21), fenced by 2 barriers.

    // epilogue: gates -> cell update in regs, h tile via LDS (stride 72)
#pragma unroll
    for (int i = 0; i < 8; ++i) {
      const int jb = jb_base + i * 16;
      const float4 bs = *(const float4*)(bsum + jb);
      const int nloc = (jb - j0) >> 2;                     // 0..63
#pragma unroll
      for (int j = 0; j < 4; ++j) {
        const int mloc = wm * 64 + j * 16 + lr;
        const float gi = acc[i][j][0] + bs.x;
        const float gf = acc[i][j][1] + bs.y;
        const float gg = acc[i][j][2] + bs.z;
        const float go = acc[i][j][3] + bs.w;
        const float cn = sigm(gf) * creg[i][j] + sigm(gi) * tanhfast(gg);
        creg[i][j] = cn;
        hlds[mloc * 72 + nloc] = f2b(sigm(go) * tanhfast(cn));
      }
    }
    __syncthreads();
    // coalesced h write: 256 rows x 64 u16 = 2048 16B chunks, 4 per thread
#pragma unroll
    for (int cc = 0; cc < 4; ++cc) {
      const int ch = tid + cc * 512;
      const int row = ch >> 3, cpos = (ch & 7) * 8;
      *(uint4*)(hout + (m0 + row) * H_ + n0 + cpos) = *(const uint4*)(hlds + row * 72 + cpos);
    }
  }
}

// Persistent decoder: 7 LSTM steps, ONE launch, 64 blocks (256^2 tiles).
// XCD x: m-block x, all 8 j-blocks -> intra-XCD h exchange; group = 8 blocks.
__launch_bounds__(512, 2)
__global__ void dec_persist_k(const u16* __restrict__ Wd, const float* __restrict__ bsd,
                              const u16* __restrict__ dz, const float* __restrict__ dcc,
                              u16* dech, unsigned* bar) {
  __shared__ u16 sh[4 * 16384];
  const int tid = threadIdx.x;
  const int lane = tid & 63, wave = tid >> 6;
  const int wj = wave >> 2, wm = wave & 3;
  const int bid = blockIdx.x;
  const int xcd = bid & 7;
  const int j0 = (bid >> 3) * 256;
  const int m0 = xcd * 256;
  unsigned* cnt = bar + (8 + xcd) * 64;

  const int lr = lane & 15;
  const int swk = ((lane >> 4) ^ ((lane >> 1) & 3)) * 8;
  const int srow = wave * 32 + (lane >> 2);
  const int csrc = ((lane & 3) ^ ((lane >> 3) & 3)) * 8;
  const u16* wsrc0 = Wd + (j0 + srow) * H_ + csrc;
  const u16* wsrc1 = wsrc0 + 16 * H_;
  u16* hlds = sh;
  const int jb_base = j0 + wj * 128 + (lane >> 4) * 4;
  const int n0 = j0 >> 2;

  float creg[8][4];
#pragma unroll
  for (int i = 0; i < 8; ++i) {
    const int n = (jb_base + i * 16) >> 2;
#pragma unroll
    for (int j = 0; j < 4; ++j)
      creg[i][j] = dcc[n * B_ + (m0 + wm * 64 + j * 16 + lr)];
  }
  WAITVM(0);   // creg loads must not pollute K-loop vmcnt accounting

  for (int t = 0; t < DEC_T_; ++t) {
    const u16* hin = t ? (dech + (long)(t - 1) * NA_) : dz;
    u16* hout = dech + (long)t * NA_;
    const u16* h0 = hin + (m0 + srow) * H_ + csrc;
    const u16* h1 = h0 + 16 * H_;

    if (t) gbar_mono(cnt, 8u * (unsigned)t);

    auto stage = [&](int kt) {
      const int b = kt & 3;
      const int k0 = kt << 5;
      u16* wd = sh + b * 16384 + wave * 1024;
      u16* ad = sh + b * 16384 + 8192 + wave * 1024;
      gl_lds16(wsrc0 + k0, wd);
      gl_lds16(wsrc1 + k0, wd + 512);
      gl_lds16c(h0 + k0, ad);
      gl_lds16c(h1 + k0, ad + 512);
    };

    f32x4 acc[8][4] = {};
    auto compute = [&](int kt) {
      const u16* Wb2 = sh + (kt & 3) * 16384;
      const u16* Ab2 = Wb2 + 8192;
      bf16x8 af[8], bb[4];
#pragma unroll
      for (int tt = 0; tt < 8; ++tt)
        af[tt] = *(const bf16x8*)(Wb2 + (wj * 128 + tt * 16 + lr) * 32 + swk);
#pragma unroll
      for (int tt = 0; tt < 4; ++tt)
        bb[tt] = *(const bf16x8*)(Ab2 + (wm * 64 + tt * 16 + lr) * 32 + swk);
#pragma unroll
      for (int i = 0; i < 8; ++i)
#pragma unroll
        for (int j = 0; j < 4; ++j)
          acc[i][j] = __builtin_amdgcn_mfma_f32_16x16x32_bf16(af[i], bb[j], acc[i][j], 0, 0, 0);
    };

    stage(0); stage(1); stage(2);
    for (int kt = 0; kt <= 16 - 4; ++kt) {                 // NT=16
      WAITVM(8); SCHED0();
      __builtin_amdgcn_s_barrier(); SCHED0();
      stage(kt + 3);
      compute(kt);
    }
    WAITVM(8); SCHED0(); __builtin_amdgcn_s_barrier(); SCHED0(); compute(13);
    WAITVM(4); SCHED0(); __builtin_amdgcn_s_barrier(); SCHED0(); compute(14);
    WAITVM(0); SCHED0(); __builtin_amdgcn_s_barrier(); SCHED0(); compute(15);

#pragma unroll
    for (int i = 0; i < 8; ++i) {
      const int jb = jb_base + i * 16;
      const float4 bs = *(const float4*)(bsd + jb);
      const int nloc = (jb - j0) >> 2;
#pragma unroll
      for (int j = 0; j < 4; ++j) {
        const int mloc = wm * 64 + j * 16 + lr;
        const float gi = acc[i][j][0] + bs.x;
        const float gf = acc[i][j][1] + bs.y;
        const float gg = acc[i][j][2] + bs.z;
        const float go = acc[i][j][3] + bs.w;
        const float cn = sigm(gf) * creg[i][j] + sigm(gi) * tanhfast(gg);
        creg[i][j] = cn;
        hlds[mloc * 72 + nloc] = f2b(sigm(go) * tanhfast(cn));
      }
    }
    __syncthreads();
#pragma unroll
    for (int cc = 0; cc < 4; ++cc) {
      const int ch = tid + cc * 512;
      const int row = ch >> 3, cpos = (ch & 7) * 8;
      *(uint4*)(hout + (m0 + row) * H_ + n0 + cpos) = *(const uint4*)(hlds + row * 72 + cpos);
    }
  }
}

// ---------------------------------------------------------------------------
// Plain bf16 GEMM + bias (verified R2 structure, unchanged).
// ldc==0 => ff mode: row m encodes (t=m>>11, b=m&2047), C index b*7V+t*V+v.
// ---------------------------------------------------------------------------
struct OP {
  const u16* A; const u16* W; const float* bias;
  float* Cf; int ldc; int K;
};

__launch_bounds__(256)
__global__ void out_mfma_k(OP p0, OP p1) {
  OP p = blockIdx.z ? p1 : p0;
  __shared__ u16 Ws[2][128 * 32];
  __shared__ u16 As[2][128 * 32];
  const int tid = threadIdx.x;
  const int lane = tid & 63, wave = tid >> 6;
  const int wr = wave & 1, wc = wave >> 1;
  const int v0 = blockIdx.x * 128, m0 = blockIdx.y * 128;
  const int lr = lane & 15;
  const int swk = ((lane >> 4) ^ ((lane >> 1) & 3)) * 8;

  const int srow = wave * 32 + (lane >> 2);
  const int csrc = ((lane & 3) ^ ((lane >> 3) & 3)) * 8;
  const u16* wsrc0 = p.W + (v0 + srow) * p.K + csrc;
  const u16* wsrc1 = wsrc0 + 16 * p.K;
  const u16* asrc0 = p.A + (m0 + srow) * p.K + csrc;
  const u16* asrc1 = asrc0 + 16 * p.K;
  u16* wdst0 = &Ws[0][(wave * 32) * 32];
  u16* wdst1 = wdst0 + 16 * 32;
  u16* adst0 = &As[0][(wave * 32) * 32];
  u16* adst1 = adst0 + 16 * 32;

  f32x4 acc[4][4] = {};
  const int NT = p.K >> 5;

  auto stage = [&](int kt, int buf) {
    const int k0 = kt << 5;
    const int bo = buf * 4096;
    gl_lds16(wsrc0 + k0, wdst0 + bo);
    gl_lds16(wsrc1 + k0, wdst1 + bo);
    gl_lds16(asrc0 + k0, adst0 + bo);
    gl_lds16(asrc1 + k0, adst1 + bo);
  };

  stage(0, 0);
  __syncthreads();
  int cur = 0;
  for (int kt = 0; kt < NT; ++kt) {
    if (kt + 1 < NT) stage(kt + 1, cur ^ 1);
    const u16* Wb = &Ws[cur][0];
    const u16* Ab = &As[cur][0];
    bf16x8 aa[4], bb[4];
#pragma unroll
    for (int t = 0; t < 4; ++t) {
      aa[t] = *(const bf16x8*)(Ab + (wr * 64 + t * 16 + lr) * 32 + swk);
      bb[t] = *(const bf16x8*)(Wb + (wc * 64 + t * 16 + lr) * 32 + swk);
    }
#pragma unroll
    for (int i = 0; i < 4; ++i)
#pragma unroll
      for (int j = 0; j < 4; ++j)
        acc[i][j] = __builtin_amdgcn_mfma_f32_16x16x32_bf16(aa[i], bb[j], acc[i][j], 0, 0, 0);
    __syncthreads();
    cur ^= 1;
  }

#pragma unroll
  for (int j = 0; j < 4; ++j) {
    const int v = v0 + wc * 64 + j * 16 + lr;
    const float bv = p.bias[v];
#pragma unroll
    for (int i = 0; i < 4; ++i) {
      const int mb = m0 + wr * 64 + i * 16 + (lane >> 4) * 4;
#pragma unroll
      for (int r = 0; r < 4; ++r) {
        const int m = mb + r;
        const float val = acc[i][j][r] + bv;
        if (p.ldc) p.Cf[m * p.ldc + v] = val;
        else p.Cf[(m & (B_ - 1)) * (DEC_T_ * V_) + (m >> 11) * V_ + v] = val;
      }
    }
  }
}

// ---- prep kernels (unchanged) ----------------------------------------------
__global__ void prep_gates_k(const float* Wih, const float* Whh,
                             const float* b1, const float* b2,
                             u16* Wout, float* bsum, int KI, int K) {
  const int j = blockIdx.y;
  const int k = blockIdx.x * 256 + threadIdx.x;
  const int worig = (j & 3) * H_ + (j >> 2);
  const float v = (k < KI) ? Wih[worig * KI + k] : Whh[worig * H_ + (k - KI)];
  Wout[(long)j * K + k] = f2b(v);
  if (k == 0) bsum[j] = b1[worig] + b2[worig];
}

__global__ void cast_k(const float* s, u16* d) {
  const int i = blockIdx.x * 256 + threadIdx.x;
  d[i] = f2b(s[i]);
}

__global__ void init_k(u16* a, u16* b, unsigned* bar) {
  const int i = blockIdx.x * 256 + threadIdx.x;
  a[i] = 0; b[i] = 0;
  if (i < 1024) bar[i] = 0u;
}

__global__ void cast_feat_k(const int* f, float* o) {
  const int i = blockIdx.x * 256 + threadIdx.x;
  o[i] = b2f(f2b((float)f[i]));
}

__global__ void ln_k(const u16* hf, const u16* hb,
                     const float* g0, const float* b0,
                     const float* g1, const float* b1,
                     u16* A0, u16* A1) {
  const int b = blockIdx.x, t = threadIdx.x;
  const int k4 = t * 4;
  const u16* src = (k4 < H_) ? (hf + b * H_ + k4) : (hb + b * H_ + (k4 - H_));
  const ushort4 raw = *(const ushort4*)src;
  const float x0 = b2f(raw.x), x1 = b2f(raw.y), x2 = b2f(raw.z), x3 = b2f(raw.w);
  float s = x0 + x1 + x2 + x3;
  float sq = x0 * x0 + x1 * x1 + x2 * x2 + x3 * x3;
#pragma unroll
  for (int off = 32; off; off >>= 1) {
    s += __shfl_down(s, off);
    sq += __shfl_down(sq, off);
  }
  __shared__ float ss[4], ssq[4], smv[2];
  if ((t & 63) == 0) { ss[t >> 6] = s; ssq[t >> 6] = sq; }
  __syncthreads();
  if (t == 0) {
    const float S = ss[0] + ss[1] + ss[2] + ss[3];
    const float SQ = ssq[0] + ssq[1] + ssq[2] + ssq[3];
    const float m = S * (1.f / 1024.f);
    const float var = SQ * (1.f / 1024.f) - m * m;
    smv[0] = m; smv[1] = rsqrtf(var + 1e-5f);
  }
  __syncthreads();
  const float m = smv[0], rs = smv[1];
  const float4 ga = *(const float4*)(g0 + k4), ba = *(const float4*)(b0 + k4);
  const float4 gb = *(const float4*)(g1 + k4), bb = *(const float4*)(b1 + k4);
  ushort4 o0, o1;
  o0.x = f2b((x0 - m) * rs * ga.x + ba.x);
  o0.y = f2b((x1 - m) * rs * ga.y + ba.y);
  o0.z = f2b((x2 - m) * rs * ga.z + ba.z);
  o0.w = f2b((x3 - m) * rs * ga.w + ba.w);
  o1.x = f2b((x0 - m) * rs * gb.x + bb.x);
  o1.y = f2b((x1 - m) * rs * gb.y + bb.y);
  o1.z = f2b((x2 - m) * rs * gb.z + bb.z);
  o1.w = f2b((x3 - m) * rs * gb.w + bb.w);
  *(ushort4*)(A0 + b * 1024 + k4) = o0;
  *(ushort4*)(A1 + b * 1024 + k4) = o1;
}

__global__ void z_k(const float* mu, const float* lv, const float* eps,
                    u16* dz, float* dc) {
  const int i = blockIdx.x * 256 + threadIdx.x;
  const float z = mu[i] + __expf(0.5f * lv[i]) * eps[i];
  dz[i] = f2b(z);
  dc[(i & (H_ - 1)) * B_ + (i >> 9)] = z;   // c transposed [H][B]
}

extern "C" void kernel_launch(void* const* d_in, const int* in_sizes, int n_in,
                              void* d_out, int out_size, void* d_ws, size_t ws_size,
                              hipStream_t stream) {
  const int*   features = (const int*)d_in[0];
  const float* eps      = (const float*)d_in[1];
  const float* emb      = (const float*)d_in[2];
  const float* eWih_f   = (const float*)d_in[3];
  const float* eWhh_f   = (const float*)d_in[4];
  const float* ebih_f   = (const float*)d_in[5];
  const float* ebhh_f   = (const float*)d_in[6];
  const float* eWih_b   = (const float*)d_in[7];
  const float* eWhh_b   = (const float*)d_in[8];
  const float* ebih_b   = (const float*)d_in[9];
  const float* ebhh_b   = (const float*)d_in[10];
  const float* dWhh     = (const float*)d_in[12];
  const float* dbih     = (const float*)d_in[13];
  const float* dbhh     = (const float*)d_in[14];
  const float* mu_ln_g  = (const float*)d_in[15];
  const float* mu_ln_b  = (const float*)d_in[16];
  const float* mu_W     = (const float*)d_in[17];
  const float* mu_b     = (const float*)d_in[18];
  const float* lv_ln_g  = (const float*)d_in[19];
  const float* lv_ln_b  = (const float*)d_in[20];
  const float* lv_W     = (const float*)d_in[21];
  const float* lv_b     = (const float*)d_in[22];
  const float* ff_W     = (const float*)d_in[23];
  const float* ff_b     = (const float*)d_in[24];

  float* of = (float*)d_out;
  float* o_feat = of;
  float* o_fh   = of + (B_ * L_);
  float* o_mu   = o_fh + (long)B_ * DEC_T_ * V_;
  float* o_lv   = o_mu + (long)B_ * H_;

  // ---- ws layout (~25.9 MB, verified R5/R7) --------------------------------
  u16* hfa = (u16*)d_ws;
  u16* hba = hfa + NA_;
  u16* hfb = hba + NA_;
  u16* hbb = hfb + NA_;
  u16* Wenc_f = hbb + NA_;                  // 2048*768
  u16* Wenc_b = Wenc_f + 2048 * 768;        // 2048*768
  u16* Wdec   = Wenc_b + 2048 * 768;        // 2048*512
  u16* Wff    = Wdec + 2048 * 512;          // 1024*512
  u16* Wmu    = Wff + 1024 * 512;           // 512*1024
  u16* Wlv    = Wmu + 512 * 1024;           // 512*1024
  u16* embb   = Wlv + 512 * 1024;           // 1024*256
  float* bsum_f = (float*)(embb + V_ * E_);
  float* bsum_b = bsum_f + 2048;
  float* bsum_d = bsum_b + 2048;
  unsigned* bar = (unsigned*)(bsum_d + 2048);  // 1024 uints
  u16* dz     = (u16*)(bar + 1024);
  float* dc   = (float*)(dz + NA_);
  u16* An0    = hfb;                        // alias (dead post-enc)
  u16* An1    = Wenc_f;                     // alias (dead post-enc)
  u16* dech   = hfa;                        // alias: 7*NA over hfa..Wenc_b

  cast_feat_k<<<dim3(B_ * L_ / 256), dim3(256), 0, stream>>>(features, o_feat);
  init_k<<<dim3(NA_ / 256), dim3(256), 0, stream>>>(hfa, hba, bar);

  prep_gates_k<<<dim3(3, 2048), dim3(256), 0, stream>>>(eWih_f, eWhh_f, ebih_f, ebhh_f, Wenc_f, bsum_f, E_, E_ + H_);
  prep_gates_k<<<dim3(3, 2048), dim3(256), 0, stream>>>(eWih_b, eWhh_b, ebih_b, ebhh_b, Wenc_b, bsum_b, E_, E_ + H_);
  prep_gates_k<<<dim3(2, 2048), dim3(256), 0, stream>>>(nullptr, dWhh, dbih, dbhh, Wdec, bsum_d, 0, H_);
  cast_k<<<dim3(1024 * 512 / 256), dim3(256), 0, stream>>>(ff_W, Wff);
  cast_k<<<dim3(512 * 1024 / 256), dim3(256), 0, stream>>>(mu_W, Wmu);
  cast_k<<<dim3(512 * 1024 / 256), dim3(256), 0, stream>>>(lv_W, Wlv);
  cast_k<<<dim3(V_ * E_ / 256), dim3(256), 0, stream>>>(emb, embb);

  // ---- encoder: ONE persistent launch (32 steps, 256^2 tiles) --------------
  enc_persist_k<<<dim3(128), dim3(512), 0, stream>>>(
      features, embb, Wenc_f, Wenc_b, bsum_f, bsum_b,
      hfa, hfb, hba, hbb, bar);
  // L=32 even -> final fwd h in hfa, bwd h in hba.

  // ---- LN + mu/lv heads ----------------------------------------------------
  ln_k<<<dim3(B_), dim3(256), 0, stream>>>(hfa, hba, mu_ln_g, mu_ln_b, lv_ln_g, lv_ln_b, An0, An1);
  {
    OP pm{}, pl{};
    pm.A = An0; pm.W = Wmu; pm.bias = mu_b; pm.Cf = o_mu; pm.ldc = H_; pm.K = 2 * H_;
    pl = pm;
    pl.A = An1; pl.W = Wlv; pl.bias = lv_b; pl.Cf = o_lv;
    out_mfma_k<<<dim3(4, 16, 2), dim3(256), 0, stream>>>(pm, pl);
  }
  z_k<<<dim3(NA_ / 256), dim3(256), 0, stream>>>(o_mu, o_lv, eps, dz, dc);

  // ---- decoder: ONE persistent launch (7 steps, 256^2 tiles) ---------------
  dec_persist_k<<<dim3(64), dim3(512), 0, stream>>>(Wdec, bsum_d, dz, dc, dech, bar);

  // ---- ONE batched ff GEMM over all 7 steps --------------------------------
  {
    OP po{};
    po.A = dech; po.W = Wff; po.bias = ff_b;
    po.Cf = o_fh; po.ldc = 0;
    po.K = H_;
    out_mfma_k<<<dim3(8, DEC_T_ * 16, 1), dim3(256), 0, stream>>>(po, po);
  }
}

// Round 9
// 1610.152 us; speedup vs baseline: 1.0551x; 1.0551x over previous
//
#include <hip/hip_runtime.h>
#include <hip/hip_bf16.h>
#include <math.h>

#define B_ 2048
#define L_ 32
#define V_ 1024
#define E_ 256
#define H_ 512
#define DEC_T_ 7
#define NA_ (B_ * H_)

typedef unsigned short u16;
typedef unsigned int u32;
using bf16x8 = __attribute__((ext_vector_type(8))) short;
using f32x4  = __attribute__((ext_vector_type(4))) float;

#define WAITVM(n) asm volatile("s_waitcnt vmcnt(" #n ")" ::: "memory")
#define SCHED0()  __builtin_amdgcn_sched_barrier(0)

__device__ __forceinline__ u16 f2b(float f) {
  union { float f; u32 i; } x; x.f = f;
  u32 r = x.i + 0x7FFFu + ((x.i >> 16) & 1u);
  return (u16)(r >> 16);
}
__device__ __forceinline__ float b2f(u16 u) {
  union { u32 i; float f; } x; x.i = ((u32)u) << 16; return x.f;
}
__device__ __forceinline__ float sigm(float x) { return 1.f / (1.f + __expf(-x)); }
__device__ __forceinline__ float tanhfast(float x) {
  const float xx = fminf(fmaxf(x, -15.f), 15.f);
  const float e = __expf(2.f * xx);
  return (e - 1.f) / (e + 1.f);
}

// async global->LDS, 16B per lane. dest = wave-uniform base + lane*16.
__device__ __forceinline__ void gl_lds16(const void* g, void* l) {
  __builtin_amdgcn_global_load_lds((const __attribute__((address_space(1))) u32*)g,
                                   (__attribute__((address_space(3))) u32*)l, 16, 0, 0);
}
// coherent variant (SC0): bypass per-CU L1 (h written by other blocks, same XCD)
__device__ __forceinline__ void gl_lds16c(const void* g, void* l) {
  __builtin_amdgcn_global_load_lds((const __attribute__((address_space(1))) u32*)g,
                                   (__attribute__((address_space(3))) u32*)l, 16, 0, 1);
}

// ---------------------------------------------------------------------------
// Per-XCD monotonic barrier (verified R5/R7/R8). No device fence -> no L2
// flush. __syncthreads drains vmcnt (h stores in L2) before signaling.
// ---------------------------------------------------------------------------
__device__ __forceinline__ void gbar_mono(unsigned* cnt, unsigned target) {
  __syncthreads();
  if (threadIdx.x == 0) {
    __hip_atomic_fetch_add(cnt, 1u, __ATOMIC_RELAXED, __HIP_MEMORY_SCOPE_AGENT);
    for (int it = 0; it < (1 << 20); ++it) {
      if (__hip_atomic_load(cnt, __ATOMIC_RELAXED, __HIP_MEMORY_SCOPE_AGENT) >= target) break;
      __builtin_amdgcn_s_sleep(2);
    }
  }
  asm volatile("" ::: "memory");
  __syncthreads();
}

// ---------------------------------------------------------------------------
// R9 encoder: occupancy-first. R8 post-mortem: 8 waves/CU (22% occ) was the
// limiter (R8 showed sublinear slowdown at 2x per-CU load; L2 at 20% of
// ceiling; schedules neutral). 128j x 64m tiles -> 1024 blocks = 4 blocks/CU
// = 16 waves/CU. 24 KB LDS/block (2-deep), launch_bounds(256,4) caps VGPR.
// Loop body = verified R2/R5 structure (syncthreads-drain; TLP hides).
// Tiles [rows][32 bf16], 16B chunks XOR-swizzled both sides (R2: 0 confl).
// ---------------------------------------------------------------------------

// Persistent bidirectional encoder: 32 LSTM steps, ONE launch, 1024 blocks.
// XCD x: dir = x>>2, m-blocks {8(x&3)..+7}, all 16 j-blocks -> h exchange
// intra-XCD; barrier group = 128 blocks. Cell state in registers.
__launch_bounds__(256, 4)
__global__ void enc_persist_k(const int* __restrict__ feat, const u16* __restrict__ emb,
                              const u16* __restrict__ Wf, const u16* __restrict__ Wbk,
                              const float* __restrict__ bsf, const float* __restrict__ bsb,
                              u16* hfa, u16* hfb, u16* hba, u16* hbb,
                              unsigned* bar) {
  __shared__ u16 Wt[2][128 * 32];   // 8 KB each
  __shared__ u16 At[2][64 * 32];    // 4 KB each  (total 24 KB)
  const int tid = threadIdx.x;
  const int lane = tid & 63, wave = tid >> 6;
  const int wr = wave & 1, wc = wave >> 1;       // wr: j half (64), wc: m half (32)
  const int bid = blockIdx.x;
  const int xcd = bid & 7;
  const int wi = bid >> 3;                       // 0..127 within XCD
  const int dir = xcd >> 2;
  const int j0 = (wi & 15) * 128;
  const int m0 = ((xcd & 3) * 8 + (wi >> 4)) * 64;
  const u16* W = dir ? Wbk : Wf;
  const float* bsum = dir ? bsb : bsf;
  u16* hA = dir ? hba : hfa;
  u16* hB = dir ? hbb : hfb;
  unsigned* cnt = bar + xcd * 64;

  const int lr = lane & 15;
  const int swk = ((lane >> 4) ^ ((lane >> 1) & 3)) * 8;   // swizzled read chunk
  const int csrc = ((lane & 3) ^ ((lane >> 3) & 3)) * 8;   // swizzled src chunk
  // W staging: wave stages W rows [wave*32, +32)  (2 gl_lds16)
  const int srowW = wave * 32 + (lane >> 2);
  const u16* wsrc0 = W + (j0 + srowW) * (E_ + H_) + csrc;
  const u16* wsrc1 = wsrc0 + 16 * (E_ + H_);
  // A staging: wave stages A rows [wave*16, +16)  (1 gl_lds16)
  const int srowA = wave * 16 + (lane >> 2);
  const int frow = (m0 + srowA) * L_;
  u16* hlds = &Wt[0][0];                                   // 64x40 = 5 KB, overlays Wt[0]
  const int jb_base = j0 + wr * 64 + (lane >> 4) * 4;
  const int n0 = j0 >> 2;                                  // block's 32-wide n range

  float creg[4][2] = {};                                   // cell state, in regs

  for (int s = 0; s < L_; ++s) {
    const int tc = dir ? (L_ - 1 - s) : s;
    const int t0 = feat[frow + tc];
    const u16* e0 = emb + t0 * E_ + csrc;
    const u16* hin = (s & 1) ? hB : hA;
    u16* hout = (s & 1) ? hA : hB;
    const u16* h0 = hin + (m0 + srowA) * H_ + csrc - E_;   // valid for k0 >= E_

    if (s) gbar_mono(cnt, 128u * (unsigned)s);             // h(s-1) visible

    auto stage = [&](int kt, int buf) {
      const int k0 = kt << 5;
      gl_lds16(wsrc0 + k0, &Wt[buf][wave * 1024]);
      gl_lds16(wsrc1 + k0, &Wt[buf][wave * 1024 + 512]);
      if (k0 < E_) gl_lds16(e0 + k0, &At[buf][wave * 512]);
      else         gl_lds16c(h0 + k0, &At[buf][wave * 512]);
    };

    f32x4 acc[4][2] = {};
    stage(0, 0);
    __syncthreads();
    int cur = 0;
    for (int kt = 0; kt < 24; ++kt) {
      if (kt + 1 < 24) stage(kt + 1, cur ^ 1);
      const u16* Wb2 = &Wt[cur][0];
      const u16* Ab2 = &At[cur][0];
      bf16x8 af[4], bb[2];
#pragma unroll
      for (int t = 0; t < 4; ++t)
        af[t] = *(const bf16x8*)(Wb2 + (wr * 64 + t * 16 + lr) * 32 + swk);
#pragma unroll
      for (int t = 0; t < 2; ++t)
        bb[t] = *(const bf16x8*)(Ab2 + (wc * 32 + t * 16 + lr) * 32 + swk);
#pragma unroll
      for (int i = 0; i < 4; ++i)
#pragma unroll
        for (int j = 0; j < 2; ++j)
          acc[i][j] = __builtin_amdgcn_mfma_f32_16x16x32_bf16(af[i], bb[j], acc[i][j], 0, 0, 0);
      __syncthreads();
      cur ^= 1;
    }
    // last compute read buf1 (kt=23); hlds overlays Wt[0] -> no collision.

    // epilogue: gates -> cell update in regs, h tile via LDS (stride 40)
#pragma unroll
    for (int i = 0; i < 4; ++i) {
      const int jb = jb_base + i * 16;
      const float4 bs = *(const float4*)(bsum + jb);
      const int nloc = (jb - j0) >> 2;                     // 0..31
#pragma unroll
      for (int j = 0; j < 2; ++j) {
        const int mloc = wc * 32 + j * 16 + lr;            // 0..63
        const float gi = acc[i][j][0] + bs.x;
        const float gf = acc[i][j][1] + bs.y;
        const float gg = acc[i][j][2] + bs.z;
        const float go = acc[i][j][3] + bs.w;
        const float cn = sigm(gf) * creg[i][j] + sigm(gi) * tanhfast(gg);
        creg[i][j] = cn;
        hlds[mloc * 40 + nloc] = f2b(sigm(go) * tanhfast(cn));
      }
    }
    __syncthreads();
    // coalesced h write: 64 rows x 64 B = 256 chunks, 1 per thread
    {
      const int row = tid >> 2, cpos = (tid & 3) * 8;
      *(uint4*)(hout + (m0 + row) * H_ + n0 + cpos) = *(const uint4*)(hlds + row * 40 + cpos);
    }
  }
}

// Persistent decoder (verified R7 build, verbatim): 7 steps, 256 blocks.
__launch_bounds__(256, 2)
__global__ void dec_persist_k(const u16* __restrict__ Wd, const float* __restrict__ bsd,
                              const u16* __restrict__ dz, const float* __restrict__ dcc,
                              u16* dech, unsigned* bar) {
  __shared__ u16 sh[4 * 8192];
  const int tid = threadIdx.x;
  const int lane = tid & 63, wave = tid >> 6;
  const int wr = wave & 1, wc = wave >> 1;
  const int bid = blockIdx.x;
  const int xcd = bid & 7;
  const int l = xcd * 32 + (bid >> 3);
  const int j0 = (l & 15) * 128;
  const int m0 = ((l >> 5) * 2 + ((l >> 4) & 1)) * 128;
  unsigned* cnt = bar + (8 + xcd) * 64;

  const int lr = lane & 15;
  const int swk = ((lane >> 4) ^ ((lane >> 1) & 3)) * 8;
  const int srow = wave * 32 + (lane >> 2);
  const int csrc = ((lane & 3) ^ ((lane >> 3) & 3)) * 8;
  const u16* wsrc0 = Wd + (j0 + srow) * H_ + csrc;
  const u16* wsrc1 = wsrc0 + 16 * H_;
  const int sw32 = (wave * 32) * 32;
  u16* hlds = sh;
  const int jb_base = j0 + wr * 64 + (lane >> 4) * 4;
  const int n0 = j0 >> 2;

  float creg[4][4];
#pragma unroll
  for (int i = 0; i < 4; ++i) {
    const int n = (jb_base + i * 16) >> 2;
#pragma unroll
    for (int j = 0; j < 4; ++j)
      creg[i][j] = dcc[n * B_ + (m0 + wc * 64 + j * 16 + lr)];
  }
  WAITVM(0);   // creg loads must not pollute K-loop vmcnt accounting

  for (int t = 0; t < DEC_T_; ++t) {
    const u16* hin = t ? (dech + (long)(t - 1) * NA_) : dz;
    u16* hout = dech + (long)t * NA_;
    const u16* h0 = hin + (m0 + srow) * H_ + csrc;
    const u16* h1 = h0 + 16 * H_;

    if (t) gbar_mono(cnt, 32u * (unsigned)t);

    auto stage = [&](int kt) {
      const int b = kt & 3;
      const int k0 = kt << 5;
      u16* wd = sh + b * 8192 + sw32;
      u16* ad = sh + b * 8192 + 4096 + sw32;
      gl_lds16(wsrc0 + k0, wd);
      gl_lds16(wsrc1 + k0, wd + 512);
      gl_lds16c(h0 + k0, ad);
      gl_lds16c(h1 + k0, ad + 512);
    };

    f32x4 acc[4][4] = {};
    auto compute = [&](int kt) {
      const u16* Wb2 = sh + (kt & 3) * 8192;
      const u16* Ab2 = Wb2 + 4096;
      bf16x8 af[4], bb[4];
#pragma unroll
      for (int tt = 0; tt < 4; ++tt) {
        af[tt] = *(const bf16x8*)(Wb2 + (wr * 64 + tt * 16 + lr) * 32 + swk);
        bb[tt] = *(const bf16x8*)(Ab2 + (wc * 64 + tt * 16 + lr) * 32 + swk);
      }
#pragma unroll
      for (int i = 0; i < 4; ++i)
#pragma unroll
        for (int j = 0; j < 4; ++j)
          acc[i][j] = __builtin_amdgcn_mfma_f32_16x16x32_bf16(af[i], bb[j], acc[i][j], 0, 0, 0);
    };

    stage(0); stage(1); stage(2);
    for (int kt = 0; kt <= 16 - 4; ++kt) {                 // NT=16
      WAITVM(8); SCHED0();
      __builtin_amdgcn_s_barrier(); SCHED0();
      stage(kt + 3);
      compute(kt);
    }
    WAITVM(8); SCHED0(); __builtin_amdgcn_s_barrier(); SCHED0(); compute(13);
    WAITVM(4); SCHED0(); __builtin_amdgcn_s_barrier(); SCHED0(); compute(14);
    WAITVM(0); SCHED0(); __builtin_amdgcn_s_barrier(); SCHED0(); compute(15);

#pragma unroll
    for (int i = 0; i < 4; ++i) {
      const int jb = jb_base + i * 16;
      const float4 bs = *(const float4*)(bsd + jb);
      const int nloc = (jb - j0) >> 2;
#pragma unroll
      for (int j = 0; j < 4; ++j) {
        const int mloc = wc * 64 + j * 16 + lr;
        const float gi = acc[i][j][0] + bs.x;
        const float gf = acc[i][j][1] + bs.y;
        const float gg = acc[i][j][2] + bs.z;
        const float go = acc[i][j][3] + bs.w;
        const float cn = sigm(gf) * creg[i][j] + sigm(gi) * tanhfast(gg);
        creg[i][j] = cn;
        hlds[mloc * 40 + nloc] = f2b(sigm(go) * tanhfast(cn));
      }
    }
    __syncthreads();
#pragma unroll
    for (int cc = 0; cc < 2; ++cc) {
      const int ch = tid + cc * 256;
      const int row = ch >> 2, cpos = (ch & 3) * 8;
      *(uint4*)(hout + (m0 + row) * H_ + n0 + cpos) = *(const uint4*)(hlds + row * 40 + cpos);
    }
  }
}

// ---------------------------------------------------------------------------
// Plain bf16 GEMM + bias (verified R2 structure, unchanged).
// ldc==0 => ff mode: row m encodes (t=m>>11, b=m&2047), C index b*7V+t*V+v.
// ---------------------------------------------------------------------------
struct OP {
  const u16* A; const u16* W; const float* bias;
  float* Cf; int ldc; int K;
};

__launch_bounds__(256)
__global__ void out_mfma_k(OP p0, OP p1) {
  OP p = blockIdx.z ? p1 : p0;
  __shared__ u16 Ws[2][128 * 32];
  __shared__ u16 As[2][128 * 32];
  const int tid = threadIdx.x;
  const int lane = tid & 63, wave = tid >> 6;
  const int wr = wave & 1, wc = wave >> 1;
  const int v0 = blockIdx.x * 128, m0 = blockIdx.y * 128;
  const int lr = lane & 15;
  const int swk = ((lane >> 4) ^ ((lane >> 1) & 3)) * 8;

  const int srow = wave * 32 + (lane >> 2);
  const int csrc = ((lane & 3) ^ ((lane >> 3) & 3)) * 8;
  const u16* wsrc0 = p.W + (v0 + srow) * p.K + csrc;
  const u16* wsrc1 = wsrc0 + 16 * p.K;
  const u16* asrc0 = p.A + (m0 + srow) * p.K + csrc;
  const u16* asrc1 = asrc0 + 16 * p.K;
  u16* wdst0 = &Ws[0][(wave * 32) * 32];
  u16* wdst1 = wdst0 + 16 * 32;
  u16* adst0 = &As[0][(wave * 32) * 32];
  u16* adst1 = adst0 + 16 * 32;

  f32x4 acc[4][4] = {};
  const int NT = p.K >> 5;

  auto stage = [&](int kt, int buf) {
    const int k0 = kt << 5;
    const int bo = buf * 4096;
    gl_lds16(wsrc0 + k0, wdst0 + bo);
    gl_lds16(wsrc1 + k0, wdst1 + bo);
    gl_lds16(asrc0 + k0, adst0 + bo);
    gl_lds16(asrc1 + k0, adst1 + bo);
  };

  stage(0, 0);
  __syncthreads();
  int cur = 0;
  for (int kt = 0; kt < NT; ++kt) {
    if (kt + 1 < NT) stage(kt + 1, cur ^ 1);
    const u16* Wb = &Ws[cur][0];
    const u16* Ab = &As[cur][0];
    bf16x8 aa[4], bb[4];
#pragma unroll
    for (int t = 0; t < 4; ++t) {
      aa[t] = *(const bf16x8*)(Ab + (wr * 64 + t * 16 + lr) * 32 + swk);
      bb[t] = *(const bf16x8*)(Wb + (wc * 64 + t * 16 + lr) * 32 + swk);
    }
#pragma unroll
    for (int i = 0; i < 4; ++i)
#pragma unroll
      for (int j = 0; j < 4; ++j)
        acc[i][j] = __builtin_amdgcn_mfma_f32_16x16x32_bf16(aa[i], bb[j], acc[i][j], 0, 0, 0);
    __syncthreads();
    cur ^= 1;
  }

#pragma unroll
  for (int j = 0; j < 4; ++j) {
    const int v = v0 + wc * 64 + j * 16 + lr;
    const float bv = p.bias[v];
#pragma unroll
    for (int i = 0; i < 4; ++i) {
      const int mb = m0 + wr * 64 + i * 16 + (lane >> 4) * 4;
#pragma unroll
      for (int r = 0; r < 4; ++r) {
        const int m = mb + r;
        const float val = acc[i][j][r] + bv;
        if (p.ldc) p.Cf[m * p.ldc + v] = val;
        else p.Cf[(m & (B_ - 1)) * (DEC_T_ * V_) + (m >> 11) * V_ + v] = val;
      }
    }
  }
}

// ---- prep kernels (unchanged) ----------------------------------------------
__global__ void prep_gates_k(const float* Wih, const float* Whh,
                             const float* b1, const float* b2,
                             u16* Wout, float* bsum, int KI, int K) {
  const int j = blockIdx.y;
  const int k = blockIdx.x * 256 + threadIdx.x;
  const int worig = (j & 3) * H_ + (j >> 2);
  const float v = (k < KI) ? Wih[worig * KI + k] : Whh[worig * H_ + (k - KI)];
  Wout[(long)j * K + k] = f2b(v);
  if (k == 0) bsum[j] = b1[worig] + b2[worig];
}

__global__ void cast_k(const float* s, u16* d) {
  const int i = blockIdx.x * 256 + threadIdx.x;
  d[i] = f2b(s[i]);
}

__global__ void init_k(u16* a, u16* b, unsigned* bar) {
  const int i = blockIdx.x * 256 + threadIdx.x;
  a[i] = 0; b[i] = 0;
  if (i < 1024) bar[i] = 0u;
}

__global__ void cast_feat_k(const int* f, float* o) {
  const int i = blockIdx.x * 256 + threadIdx.x;
  o[i] = b2f(f2b((float)f[i]));
}

__global__ void ln_k(const u16* hf, const u16* hb,
                     const float* g0, const float* b0,
                     const float* g1, const float* b1,
                     u16* A0, u16* A1) {
  const int b = blockIdx.x, t = threadIdx.x;
  const int k4 = t * 4;
  const u16* src = (k4 < H_) ? (hf + b * H_ + k4) : (hb + b * H_ + (k4 - H_));
  const ushort4 raw = *(const ushort4*)src;
  const float x0 = b2f(raw.x), x1 = b2f(raw.y), x2 = b2f(raw.z), x3 = b2f(raw.w);
  float s = x0 + x1 + x2 + x3;
  float sq = x0 * x0 + x1 * x1 + x2 * x2 + x3 * x3;
#pragma unroll
  for (int off = 32; off; off >>= 1) {
    s += __shfl_down(s, off);
    sq += __shfl_down(sq, off);
  }
  __shared__ float ss[4], ssq[4], smv[2];
  if ((t & 63) == 0) { ss[t >> 6] = s; ssq[t >> 6] = sq; }
  __syncthreads();
  if (t == 0) {
    const float S = ss[0] + ss[1] + ss[2] + ss[3];
    const float SQ = ssq[0] + ssq[1] + ssq[2] + ssq[3];
    const float m = S * (1.f / 1024.f);
    const float var = SQ * (1.f / 1024.f) - m * m;
    smv[0] = m; smv[1] = rsqrtf(var + 1e-5f);
  }
  __syncthreads();
  const float m = smv[0], rs = smv[1];
  const float4 ga = *(const float4*)(g0 + k4), ba = *(const float4*)(b0 + k4);
  const float4 gb = *(const float4*)(g1 + k4), bb = *(const float4*)(b1 + k4);
  ushort4 o0, o1;
  o0.x = f2b((x0 - m) * rs * ga.x + ba.x);
  o0.y = f2b((x1 - m) * rs * ga.y + ba.y);
  o0.z = f2b((x2 - m) * rs * ga.z + ba.z);
  o0.w = f2b((x3 - m) * rs * ga.w + ba.w);
  o1.x = f2b((x0 - m) * rs * gb.x + bb.x);
  o1.y = f2b((x1 - m) * rs * gb.y + bb.y);
  o1.z = f2b((x2 - m) * rs * gb.z + bb.z);
  o1.w = f2b((x3 - m) * rs * gb.w + bb.w);
  *(ushort4*)(A0 + b * 1024 + k4) = o0;
  *(ushort4*)(A1 + b * 1024 + k4) = o1;
}

__global__ void z_k(const float* mu, const float* lv, const float* eps,
                    u16* dz, float* dc) {
  const int i = blockIdx.x * 256 + threadIdx.x;
  const float z = mu[i] + __expf(0.5f * lv[i]) * eps[i];
  dz[i] = f2b(z);
  dc[(i & (H_ - 1)) * B_ + (i >> 9)] = z;   // c transposed [H][B]
}

extern "C" void kernel_launch(void* const* d_in, const int* in_sizes, int n_in,
                              void* d_out, int out_size, void* d_ws, size_t ws_size,
                              hipStream_t stream) {
  const int*   features = (const int*)d_in[0];
  const float* eps      = (const float*)d_in[1];
  const float* emb      = (const float*)d_in[2];
  const float* eWih_f   = (const float*)d_in[3];
  const float* eWhh_f   = (const float*)d_in[4];
  const float* ebih_f   = (const float*)d_in[5];
  const float* ebhh_f   = (const float*)d_in[6];
  const float* eWih_b   = (const float*)d_in[7];
  const float* eWhh_b   = (const float*)d_in[8];
  const float* ebih_b   = (const float*)d_in[9];
  const float* ebhh_b   = (const float*)d_in[10];
  const float* dWhh     = (const float*)d_in[12];
  const float* dbih     = (const float*)d_in[13];
  const float* dbhh     = (const float*)d_in[14];
  const float* mu_ln_g  = (const float*)d_in[15];
  const float* mu_ln_b  = (const float*)d_in[16];
  const float* mu_W     = (const float*)d_in[17];
  const float* mu_b     = (const float*)d_in[18];
  const float* lv_ln_g  = (const float*)d_in[19];
  const float* lv_ln_b  = (const float*)d_in[20];
  const float* lv_W     = (const float*)d_in[21];
  const float* lv_b     = (const float*)d_in[22];
  const float* ff_W     = (const float*)d_in[23];
  const float* ff_b     = (const float*)d_in[24];

  float* of = (float*)d_out;
  float* o_feat = of;
  float* o_fh   = of + (B_ * L_);
  float* o_mu   = o_fh + (long)B_ * DEC_T_ * V_;
  float* o_lv   = o_mu + (long)B_ * H_;

  // ---- ws layout (~25.9 MB, verified R5/R7/R8) -----------------------------
  u16* hfa = (u16*)d_ws;
  u16* hba = hfa + NA_;
  u16* hfb = hba + NA_;
  u16* hbb = hfb + NA_;
  u16* Wenc_f = hbb + NA_;                  // 2048*768
  u16* Wenc_b = Wenc_f + 2048 * 768;        // 2048*768
  u16* Wdec   = Wenc_b + 2048 * 768;        // 2048*512
  u16* Wff    = Wdec + 2048 * 512;          // 1024*512
  u16* Wmu    = Wff + 1024 * 512;           // 512*1024
  u16* Wlv    = Wmu + 512 * 1024;           // 512*1024
  u16* embb   = Wlv + 512 * 1024;           // 1024*256
  float* bsum_f = (float*)(embb + V_ * E_);
  float* bsum_b = bsum_f + 2048;
  float* bsum_d = bsum_b + 2048;
  unsigned* bar = (unsigned*)(bsum_d + 2048);  // 1024 uints
  u16* dz     = (u16*)(bar + 1024);
  float* dc   = (float*)(dz + NA_);
  u16* An0    = hfb;                        // alias (dead post-enc)
  u16* An1    = Wenc_f;                     // alias (dead post-enc)
  u16* dech   = hfa;                        // alias: 7*NA over hfa..Wenc_b

  cast_feat_k<<<dim3(B_ * L_ / 256), dim3(256), 0, stream>>>(features, o_feat);
  init_k<<<dim3(NA_ / 256), dim3(256), 0, stream>>>(hfa, hba, bar);

  prep_gates_k<<<dim3(3, 2048), dim3(256), 0, stream>>>(eWih_f, eWhh_f, ebih_f, ebhh_f, Wenc_f, bsum_f, E_, E_ + H_);
  prep_gates_k<<<dim3(3, 2048), dim3(256), 0, stream>>>(eWih_b, eWhh_b, ebih_b, ebhh_b, Wenc_b, bsum_b, E_, E_ + H_);
  prep_gates_k<<<dim3(2, 2048), dim3(256), 0, stream>>>(nullptr, dWhh, dbih, dbhh, Wdec, bsum_d, 0, H_);
  cast_k<<<dim3(1024 * 512 / 256), dim3(256), 0, stream>>>(ff_W, Wff);
  cast_k<<<dim3(512 * 1024 / 256), dim3(256), 0, stream>>>(mu_W, Wmu);
  cast_k<<<dim3(512 * 1024 / 256), dim3(256), 0, stream>>>(lv_W, Wlv);
  cast_k<<<dim3(V_ * E_ / 256), dim3(256), 0, stream>>>(emb, embb);

  // ---- encoder: ONE persistent launch (32 steps, 4 blocks/CU) --------------
  enc_persist_k<<<dim3(1024), dim3(256), 0, stream>>>(
      features, embb, Wenc_f, Wenc_b, bsum_f, bsum_b,
      hfa, hfb, hba, hbb, bar);
  // L=32 even -> final fwd h in hfa, bwd h in hba.

  // ---- LN + mu/lv heads ----------------------------------------------------
  ln_k<<<dim3(B_), dim3(256), 0, stream>>>(hfa, hba, mu_ln_g, mu_ln_b, lv_ln_g, lv_ln_b, An0, An1);
  {
    OP pm{}, pl{};
    pm.A = An0; pm.W = Wmu; pm.bias = mu_b; pm.Cf = o_mu; pm.ldc = H_; pm.K = 2 * H_;
    pl = pm;
    pl.A = An1; pl.W = Wlv; pl.bias = lv_b; pl.Cf = o_lv;
    out_mfma_k<<<dim3(4, 16, 2), dim3(256), 0, stream>>>(pm, pl);
  }
  z_k<<<dim3(NA_ / 256), dim3(256), 0, stream>>>(o_mu, o_lv, eps, dz, dc);

  // ---- decoder: ONE persistent launch (7 steps) ----------------------------
  dec_persist_k<<<dim3(256), dim3(256), 0, stream>>>(Wdec, bsum_d, dz, dc, dech, bar);

  // ---- ONE batched ff GEMM over all 7 steps --------------------------------
  {
    OP po{};
    po.A = dech; po.W = Wff; po.bias = ff_b;
    po.Cf = o_fh; po.ldc = 0;
    po.K = H_;
    out_mfma_k<<<dim3(8, DEC_T_ * 16, 1), dim3(256), 0, stream>>>(po, po);
  }
}

// Round 10
// 1056.561 us; speedup vs baseline: 1.6079x; 1.5240x over previous
//
#include <hip/hip_runtime.h>
#include <hip/hip_bf16.h>
#include <math.h>

#define B_ 2048
#define L_ 32
#define V_ 1024
#define E_ 256
#define H_ 512
#define DEC_T_ 7
#define NA_ (B_ * H_)

typedef unsigned short u16;
typedef unsigned int u32;
using bf16x8 = __attribute__((ext_vector_type(8))) short;
using f32x4  = __attribute__((ext_vector_type(4))) float;

#define WAITVM(n) asm volatile("s_waitcnt vmcnt(" #n ")" ::: "memory")
#define SCHED0()  __builtin_amdgcn_sched_barrier(0)

__device__ __forceinline__ u16 f2b(float f) {
  union { float f; u32 i; } x; x.f = f;
  u32 r = x.i + 0x7FFFu + ((x.i >> 16) & 1u);
  return (u16)(r >> 16);
}
__device__ __forceinline__ float b2f(u16 u) {
  union { u32 i; float f; } x; x.i = ((u32)u) << 16; return x.f;
}
__device__ __forceinline__ float sigm(float x) { return 1.f / (1.f + __expf(-x)); }
__device__ __forceinline__ float tanhfast(float x) {
  const float xx = fminf(fmaxf(x, -15.f), 15.f);
  const float e = __expf(2.f * xx);
  return (e - 1.f) / (e + 1.f);
}

// async global->LDS, 16B per lane. dest = wave-uniform base + lane*16.
__device__ __forceinline__ void gl_lds16(const void* g, void* l) {
  __builtin_amdgcn_global_load_lds((const __attribute__((address_space(1))) u32*)g,
                                   (__attribute__((address_space(3))) u32*)l, 16, 0, 0);
}
// coherent variant (SC0): bypass per-CU L1 (h written by other blocks, same XCD)
__device__ __forceinline__ void gl_lds16c(const void* g, void* l) {
  __builtin_amdgcn_global_load_lds((const __attribute__((address_space(1))) u32*)g,
                                   (__attribute__((address_space(3))) u32*)l, 16, 0, 1);
}

// ---------------------------------------------------------------------------
// Per-XCD monotonic barrier (verified R5-R9). No device fence -> no L2 flush.
// ---------------------------------------------------------------------------
__device__ __forceinline__ void gbar_mono(unsigned* cnt, unsigned target) {
  __syncthreads();
  if (threadIdx.x == 0) {
    __hip_atomic_fetch_add(cnt, 1u, __ATOMIC_RELAXED, __HIP_MEMORY_SCOPE_AGENT);
    for (int it = 0; it < (1 << 20); ++it) {
      if (__hip_atomic_load(cnt, __ATOMIC_RELAXED, __HIP_MEMORY_SCOPE_AGENT) >= target) break;
      __builtin_amdgcn_s_sleep(2);
    }
  }
  asm volatile("" ::: "memory");
  __syncthreads();
}

// ---------------------------------------------------------------------------
// R10 encoder: LDS-RESIDENT W. R9 post-mortem: runtime tracks FETCH volume at
// ~1 TB/s L2-fill; W panel (3.1 MB/XCD) + h streams > 4 MB L2 -> W refetched
// from L3 every step in ALL prior configs. Fix: pin each CU's 64-row W slice
// (96 KB) in LDS for all 32 steps; only act (emb|h) streams. Mapping: XCD x:
// dir=x>>2, m-range (x&3)*512 (all 32 CUs share it, all j) -> per-XCD L2
// working set ~1.3 MB, fully resident -> FETCH ~0/step. h-exchange intra-XCD.
// W LDS bank fix: row stride 1536B == 0 mod 128B -> chunk-XOR over 8
// (phys_ck = ck ^ ((row>>1)&7)), applied at the one-time cold write and on
// every ds_read. Act tile: R2-verified [rows][32] swizzle pair, double-buffer.
// LDS = 96 KB W + 2x32 KB act = 160 KB (HW max; 128 KB proven in R8).
// ---------------------------------------------------------------------------
__launch_bounds__(512, 1)
__global__ void enc_persist_k(const int* __restrict__ feat, const u16* __restrict__ emb,
                              const u16* __restrict__ Wf, const u16* __restrict__ Wbk,
                              const float* __restrict__ bsf, const float* __restrict__ bsb,
                              u16* hfa, u16* hfb, u16* hba, u16* hbb,
                              unsigned* bar) {
  __shared__ u16 Wlds[64 * 768];     // 96 KB persistent W slice
  __shared__ u16 At[2][512 * 32];    // 64 KB act double buffer
  const int tid = threadIdx.x;
  const int lane = tid & 63, wave = tid >> 6;          // 8 waves
  const int bid = blockIdx.x;                          // 256 blocks, 1/CU
  const int xcd = bid & 7;
  const int dir = xcd >> 2;
  const int m0 = (xcd & 3) * 512;                      // XCD's m-range
  const int j0 = (bid >> 3) * 64;                      // CU's 64 gate rows
  const u16* W = dir ? Wbk : Wf;
  const float* bsum = dir ? bsb : bsf;
  u16* hA = dir ? hba : hfa;
  u16* hB = dir ? hbb : hfb;
  unsigned* cnt = bar + xcd * 64;

  const int lr = lane & 15;
  const int swk = ((lane >> 4) ^ ((lane >> 1) & 3)) * 8;   // act read swizzle (R2)
  const int csrc = ((lane & 3) ^ ((lane >> 3) & 3)) * 8;   // act src swizzle (R2)
  const int xw = (lr >> 1) & 7;                            // W read bank-XOR

  // ---- one-time: load W slice into LDS (chunk-XOR layout) ------------------
  {
    const int row = tid >> 3;                          // 64 rows, 8 threads/row
    const u16* wsrc = W + (j0 + row) * (E_ + H_);
    u16* wdst = Wlds + row * 768;
    const int xr = (row >> 1) & 7;
#pragma unroll
    for (int q = 0; q < 12; ++q) {
      const int ck = (tid & 7) + q * 8;                // 96 chunks/row
      *(uint4*)(wdst + (ck ^ xr) * 8) = *(const uint4*)(wsrc + ck * 8);
    }
  }

  // act staging geometry: wave stages its own 64 m-rows (4 gl_lds16 of 16 rows)
  const int arow = lane >> 2;                          // row-in-16
  const int mbase = m0 + wave * 64;
  const int nblk = j0 >> 2;                            // block's 16 n-cols
  const int jsub = (lane >> 4) * 4;

  float creg[4][4] = {};                               // cell state, in regs
  __syncthreads();                                     // W resident

  for (int s = 0; s < L_; ++s) {
    const int tc = dir ? (L_ - 1 - s) : s;
    int tok[4];
#pragma unroll
    for (int q = 0; q < 4; ++q)
      tok[q] = feat[(mbase + q * 16 + arow) * L_ + tc];
    const u16* hin = (s & 1) ? hB : hA;
    u16* hout = (s & 1) ? hA : hB;

    if (s) gbar_mono(cnt, 32u * (unsigned)s);          // h(s-1) visible

    auto stage = [&](int kt, int buf) {
      const int k0 = kt << 5;
      u16* ad = &At[buf][(wave * 64) * 32];
#pragma unroll
      for (int q = 0; q < 4; ++q) {
        u16* dst = ad + (q * 16) * 32;
        if (k0 < E_) gl_lds16(emb + tok[q] * E_ + k0 + csrc, dst);
        else gl_lds16c(hin + (mbase + q * 16 + arow) * H_ + (k0 - E_) + csrc, dst);
      }
    };

    f32x4 acc[4][4] = {};
    stage(0, 0);
    __syncthreads();
    int cur = 0;
    for (int kt = 0; kt < 24; ++kt) {
      if (kt + 1 < 24) stage(kt + 1, cur ^ 1);
      const u16* Ab = &At[cur][0];
      const int pk = ((kt * 4 + (lane >> 4)) ^ xw) * 8;
      bf16x8 af[4], bb[4];
#pragma unroll
      for (int t = 0; t < 4; ++t)
        af[t] = *(const bf16x8*)(Wlds + (t * 16 + lr) * 768 + pk);
#pragma unroll
      for (int t = 0; t < 4; ++t)
        bb[t] = *(const bf16x8*)(Ab + (wave * 64 + t * 16 + lr) * 32 + swk);
#pragma unroll
      for (int i = 0; i < 4; ++i)
#pragma unroll
        for (int j = 0; j < 4; ++j)
          acc[i][j] = __builtin_amdgcn_mfma_f32_16x16x32_bf16(af[i], bb[j], acc[i][j], 0, 0, 0);
      __syncthreads();
      cur ^= 1;
    }

    // epilogue: gates -> cell update in regs; h tile staged in At[0] (stride 20)
    u16* hlds = &At[0][0];                             // 512 x 20 u16 = 20 KB
#pragma unroll
    for (int i = 0; i < 4; ++i) {
      const int jb = j0 + i * 16 + jsub;
      const float4 bs = *(const float4*)(bsum + jb);
      const int nloc = i * 4 + (lane >> 4);            // 0..15
#pragma unroll
      for (int j = 0; j < 4; ++j) {
        const int mloc = wave * 64 + j * 16 + lr;      // 0..511
        const float gi = acc[i][j][0] + bs.x;
        const float gf = acc[i][j][1] + bs.y;
        const float gg = acc[i][j][2] + bs.z;
        const float go = acc[i][j][3] + bs.w;
        const float cn = sigm(gf) * creg[i][j] + sigm(gi) * tanhfast(gg);
        creg[i][j] = cn;
        hlds[mloc * 20 + nloc] = f2b(sigm(go) * tanhfast(cn));
      }
    }
    __syncthreads();
    // h write: 512 rows x 32 B = 1024 16B-chunks, 2 per thread
#pragma unroll
    for (int cc = 0; cc < 2; ++cc) {
      const int ch = tid + cc * 512;
      const int row = ch >> 1, half = ch & 1;
      *(uint4*)(hout + (m0 + row) * H_ + nblk + half * 8) =
          *(const uint4*)(hlds + row * 20 + half * 8);
    }
    __syncthreads();                                   // hlds reuse (At[0]) next step
  }
}

// Persistent decoder (verified R7-R9 build, verbatim): 7 steps, 256 blocks.
__launch_bounds__(256, 2)
__global__ void dec_persist_k(const u16* __restrict__ Wd, const float* __restrict__ bsd,
                              const u16* __restrict__ dz, const float* __restrict__ dcc,
                              u16* dech, unsigned* bar) {
  __shared__ u16 sh[4 * 8192];
  const int tid = threadIdx.x;
  const int lane = tid & 63, wave = tid >> 6;
  const int wr = wave & 1, wc = wave >> 1;
  const int bid = blockIdx.x;
  const int xcd = bid & 7;
  const int l = xcd * 32 + (bid >> 3);
  const int j0 = (l & 15) * 128;
  const int m0 = ((l >> 5) * 2 + ((l >> 4) & 1)) * 128;
  unsigned* cnt = bar + (8 + xcd) * 64;

  const int lr = lane & 15;
  const int swk = ((lane >> 4) ^ ((lane >> 1) & 3)) * 8;
  const int srow = wave * 32 + (lane >> 2);
  const int csrc = ((lane & 3) ^ ((lane >> 3) & 3)) * 8;
  const u16* wsrc0 = Wd + (j0 + srow) * H_ + csrc;
  const u16* wsrc1 = wsrc0 + 16 * H_;
  const int sw32 = (wave * 32) * 32;
  u16* hlds = sh;
  const int jb_base = j0 + wr * 64 + (lane >> 4) * 4;
  const int n0 = j0 >> 2;

  float creg[4][4];
#pragma unroll
  for (int i = 0; i < 4; ++i) {
    const int n = (jb_base + i * 16) >> 2;
#pragma unroll
    for (int j = 0; j < 4; ++j)
      creg[i][j] = dcc[n * B_ + (m0 + wc * 64 + j * 16 + lr)];
  }
  WAITVM(0);   // creg loads must not pollute K-loop vmcnt accounting

  for (int t = 0; t < DEC_T_; ++t) {
    const u16* hin = t ? (dech + (long)(t - 1) * NA_) : dz;
    u16* hout = dech + (long)t * NA_;
    const u16* h0 = hin + (m0 + srow) * H_ + csrc;
    const u16* h1 = h0 + 16 * H_;

    if (t) gbar_mono(cnt, 32u * (unsigned)t);

    auto stage = [&](int kt) {
      const int b = kt & 3;
      const int k0 = kt << 5;
      u16* wd = sh + b * 8192 + sw32;
      u16* ad = sh + b * 8192 + 4096 + sw32;
      gl_lds16(wsrc0 + k0, wd);
      gl_lds16(wsrc1 + k0, wd + 512);
      gl_lds16c(h0 + k0, ad);
      gl_lds16c(h1 + k0, ad + 512);
    };

    f32x4 acc[4][4] = {};
    auto compute = [&](int kt) {
      const u16* Wb2 = sh + (kt & 3) * 8192;
      const u16* Ab2 = Wb2 + 4096;
      bf16x8 af[4], bb[4];
#pragma unroll
      for (int tt = 0; tt < 4; ++tt) {
        af[tt] = *(const bf16x8*)(Wb2 + (wr * 64 + tt * 16 + lr) * 32 + swk);
        bb[tt] = *(const bf16x8*)(Ab2 + (wc * 64 + tt * 16 + lr) * 32 + swk);
      }
#pragma unroll
      for (int i = 0; i < 4; ++i)
#pragma unroll
        for (int j = 0; j < 4; ++j)
          acc[i][j] = __builtin_amdgcn_mfma_f32_16x16x32_bf16(af[i], bb[j], acc[i][j], 0, 0, 0);
    };

    stage(0); stage(1); stage(2);
    for (int kt = 0; kt <= 16 - 4; ++kt) {                 // NT=16
      WAITVM(8); SCHED0();
      __builtin_amdgcn_s_barrier(); SCHED0();
      stage(kt + 3);
      compute(kt);
    }
    WAITVM(8); SCHED0(); __builtin_amdgcn_s_barrier(); SCHED0(); compute(13);
    WAITVM(4); SCHED0(); __builtin_amdgcn_s_barrier(); SCHED0(); compute(14);
    WAITVM(0); SCHED0(); __builtin_amdgcn_s_barrier(); SCHED0(); compute(15);

#pragma unroll
    for (int i = 0; i < 4; ++i) {
      const int jb = jb_base + i * 16;
      const float4 bs = *(const float4*)(bsd + jb);
      const int nloc = (jb - j0) >> 2;
#pragma unroll
      for (int j = 0; j < 4; ++j) {
        const int mloc = wc * 64 + j * 16 + lr;
        const float gi = acc[i][j][0] + bs.x;
        const float gf = acc[i][j][1] + bs.y;
        const float gg = acc[i][j][2] + bs.z;
        const float go = acc[i][j][3] + bs.w;
        const float cn = sigm(gf) * creg[i][j] + sigm(gi) * tanhfast(gg);
        creg[i][j] = cn;
        hlds[mloc * 40 + nloc] = f2b(sigm(go) * tanhfast(cn));
      }
    }
    __syncthreads();
#pragma unroll
    for (int cc = 0; cc < 2; ++cc) {
      const int ch = tid + cc * 256;
      const int row = ch >> 2, cpos = (ch & 3) * 8;
      *(uint4*)(hout + (m0 + row) * H_ + n0 + cpos) = *(const uint4*)(hlds + row * 40 + cpos);
    }
  }
}

// ---------------------------------------------------------------------------
// Plain bf16 GEMM + bias (verified R2 structure, unchanged).
// ldc==0 => ff mode: row m encodes (t=m>>11, b=m&2047), C index b*7V+t*V+v.
// ---------------------------------------------------------------------------
struct OP {
  const u16* A; const u16* W; const float* bias;
  float* Cf; int ldc; int K;
};

__launch_bounds__(256)
__global__ void out_mfma_k(OP p0, OP p1) {
  OP p = blockIdx.z ? p1 : p0;
  __shared__ u16 Ws[2][128 * 32];
  __shared__ u16 As[2][128 * 32];
  const int tid = threadIdx.x;
  const int lane = tid & 63, wave = tid >> 6;
  const int wr = wave & 1, wc = wave >> 1;
  const int v0 = blockIdx.x * 128, m0 = blockIdx.y * 128;
  const int lr = lane & 15;
  const int swk = ((lane >> 4) ^ ((lane >> 1) & 3)) * 8;

  const int srow = wave * 32 + (lane >> 2);
  const int csrc = ((lane & 3) ^ ((lane >> 3) & 3)) * 8;
  const u16* wsrc0 = p.W + (v0 + srow) * p.K + csrc;
  const u16* wsrc1 = wsrc0 + 16 * p.K;
  const u16* asrc0 = p.A + (m0 + srow) * p.K + csrc;
  const u16* asrc1 = asrc0 + 16 * p.K;
  u16* wdst0 = &Ws[0][(wave * 32) * 32];
  u16* wdst1 = wdst0 + 16 * 32;
  u16* adst0 = &As[0][(wave * 32) * 32];
  u16* adst1 = adst0 + 16 * 32;

  f32x4 acc[4][4] = {};
  const int NT = p.K >> 5;

  auto stage = [&](int kt, int buf) {
    const int k0 = kt << 5;
    const int bo = buf * 4096;
    gl_lds16(wsrc0 + k0, wdst0 + bo);
    gl_lds16(wsrc1 + k0, wdst1 + bo);
    gl_lds16(asrc0 + k0, adst0 + bo);
    gl_lds16(asrc1 + k0, adst1 + bo);
  };

  stage(0, 0);
  __syncthreads();
  int cur = 0;
  for (int kt = 0; kt < NT; ++kt) {
    if (kt + 1 < NT) stage(kt + 1, cur ^ 1);
    const u16* Wb = &Ws[cur][0];
    const u16* Ab = &As[cur][0];
    bf16x8 aa[4], bb[4];
#pragma unroll
    for (int t = 0; t < 4; ++t) {
      aa[t] = *(const bf16x8*)(Ab + (wr * 64 + t * 16 + lr) * 32 + swk);
      bb[t] = *(const bf16x8*)(Wb + (wc * 64 + t * 16 + lr) * 32 + swk);
    }
#pragma unroll
    for (int i = 0; i < 4; ++i)
#pragma unroll
      for (int j = 0; j < 4; ++j)
        acc[i][j] = __builtin_amdgcn_mfma_f32_16x16x32_bf16(aa[i], bb[j], acc[i][j], 0, 0, 0);
    __syncthreads();
    cur ^= 1;
  }

#pragma unroll
  for (int j = 0; j < 4; ++j) {
    const int v = v0 + wc * 64 + j * 16 + lr;
    const float bv = p.bias[v];
#pragma unroll
    for (int i = 0; i < 4; ++i) {
      const int mb = m0 + wr * 64 + i * 16 + (lane >> 4) * 4;
#pragma unroll
      for (int r = 0; r < 4; ++r) {
        const int m = mb + r;
        const float val = acc[i][j][r] + bv;
        if (p.ldc) p.Cf[m * p.ldc + v] = val;
        else p.Cf[(m & (B_ - 1)) * (DEC_T_ * V_) + (m >> 11) * V_ + v] = val;
      }
    }
  }
}

// ---- prep kernels (unchanged) ----------------------------------------------
__global__ void prep_gates_k(const float* Wih, const float* Whh,
                             const float* b1, const float* b2,
                             u16* Wout, float* bsum, int KI, int K) {
  const int j = blockIdx.y;
  const int k = blockIdx.x * 256 + threadIdx.x;
  const int worig = (j & 3) * H_ + (j >> 2);
  const float v = (k < KI) ? Wih[worig * KI + k] : Whh[worig * H_ + (k - KI)];
  Wout[(long)j * K + k] = f2b(v);
  if (k == 0) bsum[j] = b1[worig] + b2[worig];
}

__global__ void cast_k(const float* s, u16* d) {
  const int i = blockIdx.x * 256 + threadIdx.x;
  d[i] = f2b(s[i]);
}

__global__ void init_k(u16* a, u16* b, unsigned* bar) {
  const int i = blockIdx.x * 256 + threadIdx.x;
  a[i] = 0; b[i] = 0;
  if (i < 1024) bar[i] = 0u;
}

__global__ void cast_feat_k(const int* f, float* o) {
  const int i = blockIdx.x * 256 + threadIdx.x;
  o[i] = b2f(f2b((float)f[i]));
}

__global__ void ln_k(const u16* hf, const u16* hb,
                     const float* g0, const float* b0,
                     const float* g1, const float* b1,
                     u16* A0, u16* A1) {
  const int b = blockIdx.x, t = threadIdx.x;
  const int k4 = t * 4;
  const u16* src = (k4 < H_) ? (hf + b * H_ + k4) : (hb + b * H_ + (k4 - H_));
  const ushort4 raw = *(const ushort4*)src;
  const float x0 = b2f(raw.x), x1 = b2f(raw.y), x2 = b2f(raw.z), x3 = b2f(raw.w);
  float s = x0 + x1 + x2 + x3;
  float sq = x0 * x0 + x1 * x1 + x2 * x2 + x3 * x3;
#pragma unroll
  for (int off = 32; off; off >>= 1) {
    s += __shfl_down(s, off);
    sq += __shfl_down(sq, off);
  }
  __shared__ float ss[4], ssq[4], smv[2];
  if ((t & 63) == 0) { ss[t >> 6] = s; ssq[t >> 6] = sq; }
  __syncthreads();
  if (t == 0) {
    const float S = ss[0] + ss[1] + ss[2] + ss[3];
    const float SQ = ssq[0] + ssq[1] + ssq[2] + ssq[3];
    const float m = S * (1.f / 1024.f);
    const float var = SQ * (1.f / 1024.f) - m * m;
    smv[0] = m; smv[1] = rsqrtf(var + 1e-5f);
  }
  __syncthreads();
  const float m = smv[0], rs = smv[1];
  const float4 ga = *(const float4*)(g0 + k4), ba = *(const float4*)(b0 + k4);
  const float4 gb = *(const float4*)(g1 + k4), bb = *(const float4*)(b1 + k4);
  ushort4 o0, o1;
  o0.x = f2b((x0 - m) * rs * ga.x + ba.x);
  o0.y = f2b((x1 - m) * rs * ga.y + ba.y);
  o0.z = f2b((x2 - m) * rs * ga.z + ba.z);
  o0.w = f2b((x3 - m) * rs * ga.w + ba.w);
  o1.x = f2b((x0 - m) * rs * gb.x + bb.x);
  o1.y = f2b((x1 - m) * rs * gb.y + bb.y);
  o1.z = f2b((x2 - m) * rs * gb.z + bb.z);
  o1.w = f2b((x3 - m) * rs * gb.w + bb.w);
  *(ushort4*)(A0 + b * 1024 + k4) = o0;
  *(ushort4*)(A1 + b * 1024 + k4) = o1;
}

__global__ void z_k(const float* mu, const float* lv, const float* eps,
                    u16* dz, float* dc) {
  const int i = blockIdx.x * 256 + threadIdx.x;
  const float z = mu[i] + __expf(0.5f * lv[i]) * eps[i];
  dz[i] = f2b(z);
  dc[(i & (H_ - 1)) * B_ + (i >> 9)] = z;   // c transposed [H][B]
}

extern "C" void kernel_launch(void* const* d_in, const int* in_sizes, int n_in,
                              void* d_out, int out_size, void* d_ws, size_t ws_size,
                              hipStream_t stream) {
  const int*   features = (const int*)d_in[0];
  const float* eps      = (const float*)d_in[1];
  const float* emb      = (const float*)d_in[2];
  const float* eWih_f   = (const float*)d_in[3];
  const float* eWhh_f   = (const float*)d_in[4];
  const float* ebih_f   = (const float*)d_in[5];
  const float* ebhh_f   = (const float*)d_in[6];
  const float* eWih_b   = (const float*)d_in[7];
  const float* eWhh_b   = (const float*)d_in[8];
  const float* ebih_b   = (const float*)d_in[9];
  const float* ebhh_b   = (const float*)d_in[10];
  const float* dWhh     = (const float*)d_in[12];
  const float* dbih     = (const float*)d_in[13];
  const float* dbhh     = (const float*)d_in[14];
  const float* mu_ln_g  = (const float*)d_in[15];
  const float* mu_ln_b  = (const float*)d_in[16];
  const float* mu_W     = (const float*)d_in[17];
  const float* mu_b     = (const float*)d_in[18];
  const float* lv_ln_g  = (const float*)d_in[19];
  const float* lv_ln_b  = (const float*)d_in[20];
  const float* lv_W     = (const float*)d_in[21];
  const float* lv_b     = (const float*)d_in[22];
  const float* ff_W     = (const float*)d_in[23];
  const float* ff_b     = (const float*)d_in[24];

  float* of = (float*)d_out;
  float* o_feat = of;
  float* o_fh   = of + (B_ * L_);
  float* o_mu   = o_fh + (long)B_ * DEC_T_ * V_;
  float* o_lv   = o_mu + (long)B_ * H_;

  // ---- ws layout (~25.9 MB, verified R5-R9) --------------------------------
  u16* hfa = (u16*)d_ws;
  u16* hba = hfa + NA_;
  u16* hfb = hba + NA_;
  u16* hbb = hfb + NA_;
  u16* Wenc_f = hbb + NA_;                  // 2048*768
  u16* Wenc_b = Wenc_f + 2048 * 768;        // 2048*768
  u16* Wdec   = Wenc_b + 2048 * 768;        // 2048*512
  u16* Wff    = Wdec + 2048 * 512;          // 1024*512
  u16* Wmu    = Wff + 1024 * 512;           // 512*1024
  u16* Wlv    = Wmu + 512 * 1024;           // 512*1024
  u16* embb   = Wlv + 512 * 1024;           // 1024*256
  float* bsum_f = (float*)(embb + V_ * E_);
  float* bsum_b = bsum_f + 2048;
  float* bsum_d = bsum_b + 2048;
  unsigned* bar = (unsigned*)(bsum_d + 2048);  // 1024 uints
  u16* dz     = (u16*)(bar + 1024);
  float* dc   = (float*)(dz + NA_);
  u16* An0    = hfb;                        // alias (dead post-enc)
  u16* An1    = Wenc_f;                     // alias (dead post-enc)
  u16* dech   = hfa;                        // alias: 7*NA over hfa..Wenc_b

  cast_feat_k<<<dim3(B_ * L_ / 256), dim3(256), 0, stream>>>(features, o_feat);
  init_k<<<dim3(NA_ / 256), dim3(256), 0, stream>>>(hfa, hba, bar);

  prep_gates_k<<<dim3(3, 2048), dim3(256), 0, stream>>>(eWih_f, eWhh_f, ebih_f, ebhh_f, Wenc_f, bsum_f, E_, E_ + H_);
  prep_gates_k<<<dim3(3, 2048), dim3(256), 0, stream>>>(eWih_b, eWhh_b, ebih_b, ebhh_b, Wenc_b, bsum_b, E_, E_ + H_);
  prep_gates_k<<<dim3(2, 2048), dim3(256), 0, stream>>>(nullptr, dWhh, dbih, dbhh, Wdec, bsum_d, 0, H_);
  cast_k<<<dim3(1024 * 512 / 256), dim3(256), 0, stream>>>(ff_W, Wff);
  cast_k<<<dim3(512 * 1024 / 256), dim3(256), 0, stream>>>(mu_W, Wmu);
  cast_k<<<dim3(512 * 1024 / 256), dim3(256), 0, stream>>>(lv_W, Wlv);
  cast_k<<<dim3(V_ * E_ / 256), dim3(256), 0, stream>>>(emb, embb);

  // ---- encoder: ONE persistent launch, W resident in LDS -------------------
  enc_persist_k<<<dim3(256), dim3(512), 0, stream>>>(
      features, embb, Wenc_f, Wenc_b, bsum_f, bsum_b,
      hfa, hfb, hba, hbb, bar);
  // L=32 even -> final fwd h in hfa, bwd h in hba.

  // ---- LN + mu/lv heads ----------------------------------------------------
  ln_k<<<dim3(B_), dim3(256), 0, stream>>>(hfa, hba, mu_ln_g, mu_ln_b, lv_ln_g, lv_ln_b, An0, An1);
  {
    OP pm{}, pl{};
    pm.A = An0; pm.W = Wmu; pm.bias = mu_b; pm.Cf = o_mu; pm.ldc = H_; pm.K = 2 * H_;
    pl = pm;
    pl.A = An1; pl.W = Wlv; pl.bias = lv_b; pl.Cf = o_lv;
    out_mfma_k<<<dim3(4, 16, 2), dim3(256), 0, stream>>>(pm, pl);
  }
  z_k<<<dim3(NA_ / 256), dim3(256), 0, stream>>>(o_mu, o_lv, eps, dz, dc);

  // ---- decoder: ONE persistent launch (7 steps) ----------------------------
  dec_persist_k<<<dim3(256), dim3(256), 0, stream>>>(Wdec, bsum_d, dz, dc, dech, bar);

  // ---- ONE batched ff GEMM over all 7 steps --------------------------------
  {
    OP po{};
    po.A = dech; po.W = Wff; po.bias = ff_b;
    po.Cf = o_fh; po.ldc = 0;
    po.K = H_;
    out_mfma_k<<<dim3(8, DEC_T_ * 16, 1), dim3(256), 0, stream>>>(po, po);
  }
}

// Round 11
// 861.514 us; speedup vs baseline: 1.9719x; 1.2264x over previous
//
#include <hip/hip_runtime.h>
#include <hip/hip_bf16.h>
#include <math.h>

#define B_ 2048
#define L_ 32
#define V_ 1024
#define E_ 256
#define H_ 512
#define DEC_T_ 7
#define NA_ (B_ * H_)

typedef unsigned short u16;
typedef unsigned int u32;
using bf16x8 = __attribute__((ext_vector_type(8))) short;
using f32x4  = __attribute__((ext_vector_type(4))) float;

#define WAITVM(n) asm volatile("s_waitcnt vmcnt(" #n ")" ::: "memory")
#define WAITLG0() asm volatile("s_waitcnt lgkmcnt(0)" ::: "memory")
#define SCHED0()  __builtin_amdgcn_sched_barrier(0)

__device__ __forceinline__ u16 f2b(float f) {
  union { float f; u32 i; } x; x.f = f;
  u32 r = x.i + 0x7FFFu + ((x.i >> 16) & 1u);
  return (u16)(r >> 16);
}
__device__ __forceinline__ float b2f(u16 u) {
  union { u32 i; float f; } x; x.i = ((u32)u) << 16; return x.f;
}
__device__ __forceinline__ float sigm(float x) { return 1.f / (1.f + __expf(-x)); }
__device__ __forceinline__ float tanhfast(float x) {
  const float xx = fminf(fmaxf(x, -15.f), 15.f);
  const float e = __expf(2.f * xx);
  return (e - 1.f) / (e + 1.f);
}

// async global->LDS, 16B per lane. dest = wave-uniform base + lane*16.
__device__ __forceinline__ void gl_lds16(const void* g, void* l) {
  __builtin_amdgcn_global_load_lds((const __attribute__((address_space(1))) u32*)g,
                                   (__attribute__((address_space(3))) u32*)l, 16, 0, 0);
}
// coherent variant (SC0): bypass per-CU L1 (h written by other blocks, same XCD)
__device__ __forceinline__ void gl_lds16c(const void* g, void* l) {
  __builtin_amdgcn_global_load_lds((const __attribute__((address_space(1))) u32*)g,
                                   (__attribute__((address_space(3))) u32*)l, 16, 0, 1);
}

// ---------------------------------------------------------------------------
// Per-XCD monotonic barrier (verified R5-R10). No device fence -> no L2 flush.
// First __syncthreads drains vmcnt -> all waves' h-stores in L2 before signal.
// ---------------------------------------------------------------------------
__device__ __forceinline__ void gbar_mono(unsigned* cnt, unsigned target) {
  __syncthreads();
  if (threadIdx.x == 0) {
    __hip_atomic_fetch_add(cnt, 1u, __ATOMIC_RELAXED, __HIP_MEMORY_SCOPE_AGENT);
    for (int it = 0; it < (1 << 20); ++it) {
      if (__hip_atomic_load(cnt, __ATOMIC_RELAXED, __HIP_MEMORY_SCOPE_AGENT) >= target) break;
      __builtin_amdgcn_s_sleep(2);
    }
  }
  asm volatile("" ::: "memory");
  __syncthreads();
}

// ---------------------------------------------------------------------------
// R11 encoder: BARRIER-FREE K-loop. R10 post-mortem: FETCH ~0 yet time
// unchanged -> stall is the 24 per-kt vmcnt-draining __syncthreads with only
// 2 lockstep waves/SIMD (per-kt 2750 cy vs ~900 floor). Fix: act tiles are
// WAVE-PRIVATE (each wave stages only the 64 m-rows it consumes) -> producer
// == consumer -> per-wave counted WAITVM(4) replaces ALL block barriers in
// the K-loop. Depth-2 private pipeline; buffer overwrite guarded by
// lgkmcnt(0) before re-stage (async LDS-write lands >=300cy after issue,
// ds_reads already retired). One gbar per step; first 6 kt (emb-only,
// h-independent) run BEFORE it, hiding barrier skew. W LDS-resident (96 KB,
// R10-verified chunk-XOR). LDS = 96 + 8 waves x 2 x 4 KB = 160 KB.
// ---------------------------------------------------------------------------
__launch_bounds__(512, 1)
__global__ void enc_persist_k(const int* __restrict__ feat, const u16* __restrict__ emb,
                              const u16* __restrict__ Wf, const u16* __restrict__ Wbk,
                              const float* __restrict__ bsf, const float* __restrict__ bsb,
                              u16* hfa, u16* hfb, u16* hba, u16* hbb,
                              unsigned* bar) {
  __shared__ u16 Wlds[64 * 768];       // 96 KB persistent W slice
  __shared__ u16 At[8][2][2048];       // 64 KB: per-wave private dbuf (64r x 32k)
  const int tid = threadIdx.x;
  const int lane = tid & 63, wave = tid >> 6;          // 8 waves
  const int bid = blockIdx.x;                          // 256 blocks, 1/CU
  const int xcd = bid & 7;
  const int dir = xcd >> 2;
  const int m0 = (xcd & 3) * 512;
  const int j0 = (bid >> 3) * 64;
  const u16* W = dir ? Wbk : Wf;
  const float* bsum = dir ? bsb : bsf;
  u16* hA = dir ? hba : hfa;
  u16* hB = dir ? hbb : hfb;
  unsigned* cnt = bar + xcd * 64;

  const int lr = lane & 15, hi = lane >> 4;
  const int swk = (hi ^ ((lane >> 1) & 3)) * 8;        // act read swizzle (R2)
  const int csrc = ((lane & 3) ^ ((lane >> 3) & 3)) * 8; // act src swizzle (R2)
  const int xw = (lr >> 1) & 7;                        // W read bank-XOR (R10)
  const int arow = lane >> 2;
  const int mw0 = m0 + wave * 64;                      // wave's private m-rows
  const int n0 = j0 >> 2;
  const int jsub = hi * 4;

  // ---- one-time: load W slice into LDS (R10-verified chunk-XOR layout) -----
  {
    const int row = tid >> 3;
    const u16* wsrc = W + (j0 + row) * (E_ + H_);
    u16* wdst = Wlds + row * 768;
    const int xr = (row >> 1) & 7;
#pragma unroll
    for (int q = 0; q < 12; ++q) {
      const int ck = (tid & 7) + q * 8;
      *(uint4*)(wdst + (ck ^ xr) * 8) = *(const uint4*)(wsrc + ck * 8);
    }
  }
  float creg[4][4] = {};
  __syncthreads();                                     // W resident

  for (int s = 0; s < L_; ++s) {
    const int tc = dir ? (L_ - 1 - s) : s;
    int tok[4];
#pragma unroll
    for (int q = 0; q < 4; ++q)
      tok[q] = feat[(mw0 + q * 16 + arow) * L_ + tc];
    const u16* hin = (s & 1) ? hB : hA;
    u16* hout = (s & 1) ? hA : hB;

    auto stage = [&](int kt, int buf) {
      const int k0 = kt << 5;
      u16* ad = &At[wave][buf][0];
#pragma unroll
      for (int q = 0; q < 4; ++q) {
        u16* dst = ad + (q * 16) * 32;
        if (k0 < E_) gl_lds16(emb + tok[q] * E_ + k0 + csrc, dst);
        else gl_lds16c(hin + (mw0 + q * 16 + arow) * H_ + (k0 - E_) + csrc, dst);
      }
    };

    f32x4 acc[4][4] = {};
    auto compute = [&](int kt) {
      const int pk = ((kt * 4 + hi) ^ xw) * 8;
      const u16* Ab = &At[wave][kt & 1][0];
      bf16x8 af[4], bb[4];
#pragma unroll
      for (int t = 0; t < 4; ++t)
        af[t] = *(const bf16x8*)(Wlds + (t * 16 + lr) * 768 + pk);
#pragma unroll
      for (int t = 0; t < 4; ++t)
        bb[t] = *(const bf16x8*)(Ab + (t * 16 + lr) * 32 + swk);
      WAITLG0(); SCHED0();                 // reads retired -> buf free
      if (kt + 2 < 24) stage(kt + 2, kt & 1);
#pragma unroll
      for (int i = 0; i < 4; ++i)
#pragma unroll
        for (int j = 0; j < 4; ++j)
          acc[i][j] = __builtin_amdgcn_mfma_f32_16x16x32_bf16(af[i], bb[j], acc[i][j], 0, 0, 0);
    };

    stage(0, 0); stage(1, 1);                          // 8 loads in flight
    for (int kt = 0; kt < 6; ++kt) {                   // emb-only, pre-barrier
      WAITVM(4); SCHED0();
      compute(kt);
    }
    if (s) gbar_mono(cnt, 32u * (unsigned)s);          // h(s-1) visible; drains vmcnt (safe: WAITVM is upper bound)
    for (int kt = 6; kt < 23; ++kt) {
      WAITVM(4); SCHED0();
      compute(kt);
    }
    WAITVM(0); SCHED0();
    compute(23);

    // epilogue (wave-private): gates -> cell update; h via own LDS region
    u16* hld = &At[wave][0][0];                        // 64 rows x stride 20
#pragma unroll
    for (int i = 0; i < 4; ++i) {
      const int jb = j0 + i * 16 + jsub;
      const float4 bs = *(const float4*)(bsum + jb);
      const int nloc = i * 4 + hi;                     // 0..15
#pragma unroll
      for (int j = 0; j < 4; ++j) {
        const int mloc = j * 16 + lr;                  // 0..63 (wave-local)
        const float gi = acc[i][j][0] + bs.x;
        const float gf = acc[i][j][1] + bs.y;
        const float gg = acc[i][j][2] + bs.z;
        const float go = acc[i][j][3] + bs.w;
        const float cn = sigm(gf) * creg[i][j] + sigm(gi) * tanhfast(gg);
        creg[i][j] = cn;
        hld[mloc * 20 + nloc] = f2b(sigm(go) * tanhfast(cn));
      }
    }
    WAITLG0(); SCHED0();                               // cross-lane LDS visibility (same wave)
    // coalesced h write: 64 rows x 32 B = 128 chunks, 2 per lane
#pragma unroll
    for (int c = 0; c < 2; ++c) {
      const int idx = lane + c * 64;
      const int row = idx >> 1, half = idx & 1;
      *(uint4*)(hout + (mw0 + row) * H_ + n0 + half * 8) =
          *(const uint4*)(hld + row * 20 + half * 8);
    }
  }
}

// R11 decoder: same barrier-free wave-private template. K=512, W 64 KB LDS,
// per-wave m-slice 32 (2 gl_lds16/stage -> WAITVM(2)). 256 blocks, 1/CU.
// XCD x: m0 = x*256, j covered by 32 blocks/XCD -> intra-XCD h exchange.
__launch_bounds__(512, 1)
__global__ void dec_persist_k(const u16* __restrict__ Wd, const float* __restrict__ bsd,
                              const u16* __restrict__ dz, const float* __restrict__ dcc,
                              u16* dech, unsigned* bar) {
  __shared__ u16 Wlds[64 * 512];       // 64 KB
  __shared__ u16 At[8][2][1024];       // 16 KB: per-wave dbuf (32r x 32k)
  const int tid = threadIdx.x;
  const int lane = tid & 63, wave = tid >> 6;
  const int bid = blockIdx.x;
  const int xcd = bid & 7;
  const int m0 = xcd * 256;
  const int j0 = (bid >> 3) * 64;
  unsigned* cnt = bar + (8 + xcd) * 64;

  const int lr = lane & 15, hi = lane >> 4;
  const int swk = (hi ^ ((lane >> 1) & 3)) * 8;
  const int csrc = ((lane & 3) ^ ((lane >> 3) & 3)) * 8;
  const int xw = (lr >> 1) & 7;
  const int arow = lane >> 2;
  const int mw0 = m0 + wave * 32;
  const int n0 = j0 >> 2;
  const int jsub = hi * 4;

  {  // one-time W load, chunk-XOR (row stride 1024B == 0 mod 128B)
    const int row = tid >> 3;
    const u16* wsrc = Wd + (j0 + row) * H_;
    u16* wdst = Wlds + row * 512;
    const int xr = (row >> 1) & 7;
#pragma unroll
    for (int q = 0; q < 8; ++q) {
      const int ck = (tid & 7) + q * 8;
      *(uint4*)(wdst + (ck ^ xr) * 8) = *(const uint4*)(wsrc + ck * 8);
    }
  }

  float creg[4][2];
#pragma unroll
  for (int i = 0; i < 4; ++i) {
    const int n = (j0 + i * 16 + jsub) >> 2;
#pragma unroll
    for (int j = 0; j < 2; ++j)
      creg[i][j] = dcc[n * B_ + (mw0 + j * 16 + lr)];
  }
  WAITVM(0);                                           // clean vmcnt accounting
  __syncthreads();                                     // W resident

  for (int t = 0; t < DEC_T_; ++t) {
    const u16* hin = t ? (dech + (long)(t - 1) * NA_) : dz;
    u16* hout = dech + (long)t * NA_;

    if (t) gbar_mono(cnt, 32u * (unsigned)t);          // h(t-1) visible

    auto stage = [&](int kt, int buf) {
      const int k0 = kt << 5;
      u16* ad = &At[wave][buf][0];
#pragma unroll
      for (int q = 0; q < 2; ++q)
        gl_lds16c(hin + (mw0 + q * 16 + arow) * H_ + k0 + csrc, ad + (q * 16) * 32);
    };

    f32x4 acc[4][2] = {};
    auto compute = [&](int kt) {
      const int pk = ((kt * 4 + hi) ^ xw) * 8;
      const u16* Ab = &At[wave][kt & 1][0];
      bf16x8 af[4], bb[2];
#pragma unroll
      for (int tt = 0; tt < 4; ++tt)
        af[tt] = *(const bf16x8*)(Wlds + (tt * 16 + lr) * 512 + pk);
#pragma unroll
      for (int tt = 0; tt < 2; ++tt)
        bb[tt] = *(const bf16x8*)(Ab + (tt * 16 + lr) * 32 + swk);
      WAITLG0(); SCHED0();
      if (kt + 2 < 16) stage(kt + 2, kt & 1);
#pragma unroll
      for (int i = 0; i < 4; ++i)
#pragma unroll
        for (int j = 0; j < 2; ++j)
          acc[i][j] = __builtin_amdgcn_mfma_f32_16x16x32_bf16(af[i], bb[j], acc[i][j], 0, 0, 0);
    };

    stage(0, 0); stage(1, 1);
    for (int kt = 0; kt < 15; ++kt) {
      WAITVM(2); SCHED0();
      compute(kt);
    }
    WAITVM(0); SCHED0();
    compute(15);

    u16* hld = &At[wave][0][0];                        // 32 rows x stride 20
#pragma unroll
    for (int i = 0; i < 4; ++i) {
      const int jb = j0 + i * 16 + jsub;
      const float4 bs = *(const float4*)(bsd + jb);
      const int nloc = i * 4 + hi;
#pragma unroll
      for (int j = 0; j < 2; ++j) {
        const int mloc = j * 16 + lr;                  // 0..31
        const float gi = acc[i][j][0] + bs.x;
        const float gf = acc[i][j][1] + bs.y;
        const float gg = acc[i][j][2] + bs.z;
        const float go = acc[i][j][3] + bs.w;
        const float cn = sigm(gf) * creg[i][j] + sigm(gi) * tanhfast(gg);
        creg[i][j] = cn;
        hld[mloc * 20 + nloc] = f2b(sigm(go) * tanhfast(cn));
      }
    }
    WAITLG0(); SCHED0();
    {                                                  // 32 rows x 2 halves = 64 chunks
      const int row = lane >> 1, half = lane & 1;
      *(uint4*)(hout + (mw0 + row) * H_ + n0 + half * 8) =
          *(const uint4*)(hld + row * 20 + half * 8);
    }
  }
}

// ---------------------------------------------------------------------------
// Plain bf16 GEMM + bias (verified R2 structure, unchanged).
// ldc==0 => ff mode: row m encodes (t=m>>11, b=m&2047), C index b*7V+t*V+v.
// ---------------------------------------------------------------------------
struct OP {
  const u16* A; const u16* W; const float* bias;
  float* Cf; int ldc; int K;
};

__launch_bounds__(256)
__global__ void out_mfma_k(OP p0, OP p1) {
  OP p = blockIdx.z ? p1 : p0;
  __shared__ u16 Ws[2][128 * 32];
  __shared__ u16 As[2][128 * 32];
  const int tid = threadIdx.x;
  const int lane = tid & 63, wave = tid >> 6;
  const int wr = wave & 1, wc = wave >> 1;
  const int v0 = blockIdx.x * 128, m0 = blockIdx.y * 128;
  const int lr = lane & 15;
  const int swk = ((lane >> 4) ^ ((lane >> 1) & 3)) * 8;

  const int srow = wave * 32 + (lane >> 2);
  const int csrc = ((lane & 3) ^ ((lane >> 3) & 3)) * 8;
  const u16* wsrc0 = p.W + (v0 + srow) * p.K + csrc;
  const u16* wsrc1 = wsrc0 + 16 * p.K;
  const u16* asrc0 = p.A + (m0 + srow) * p.K + csrc;
  const u16* asrc1 = asrc0 + 16 * p.K;
  u16* wdst0 = &Ws[0][(wave * 32) * 32];
  u16* wdst1 = wdst0 + 16 * 32;
  u16* adst0 = &As[0][(wave * 32) * 32];
  u16* adst1 = adst0 + 16 * 32;

  f32x4 acc[4][4] = {};
  const int NT = p.K >> 5;

  auto stage = [&](int kt, int buf) {
    const int k0 = kt << 5;
    const int bo = buf * 4096;
    gl_lds16(wsrc0 + k0, wdst0 + bo);
    gl_lds16(wsrc1 + k0, wdst1 + bo);
    gl_lds16(asrc0 + k0, adst0 + bo);
    gl_lds16(asrc1 + k0, adst1 + bo);
  };

  stage(0, 0);
  __syncthreads();
  int cur = 0;
  for (int kt = 0; kt < NT; ++kt) {
    if (kt + 1 < NT) stage(kt + 1, cur ^ 1);
    const u16* Wb = &Ws[cur][0];
    const u16* Ab = &As[cur][0];
    bf16x8 aa[4], bb[4];
#pragma unroll
    for (int t = 0; t < 4; ++t) {
      aa[t] = *(const bf16x8*)(Ab + (wr * 64 + t * 16 + lr) * 32 + swk);
      bb[t] = *(const bf16x8*)(Wb + (wc * 64 + t * 16 + lr) * 32 + swk);
    }
#pragma unroll
    for (int i = 0; i < 4; ++i)
#pragma unroll
      for (int j = 0; j < 4; ++j)
        acc[i][j] = __builtin_amdgcn_mfma_f32_16x16x32_bf16(aa[i], bb[j], acc[i][j], 0, 0, 0);
    __syncthreads();
    cur ^= 1;
  }

#pragma unroll
  for (int j = 0; j < 4; ++j) {
    const int v = v0 + wc * 64 + j * 16 + lr;
    const float bv = p.bias[v];
#pragma unroll
    for (int i = 0; i < 4; ++i) {
      const int mb = m0 + wr * 64 + i * 16 + (lane >> 4) * 4;
#pragma unroll
      for (int r = 0; r < 4; ++r) {
        const int m = mb + r;
        const float val = acc[i][j][r] + bv;
        if (p.ldc) p.Cf[m * p.ldc + v] = val;
        else p.Cf[(m & (B_ - 1)) * (DEC_T_ * V_) + (m >> 11) * V_ + v] = val;
      }
    }
  }
}

// ---- prep kernels (unchanged) ----------------------------------------------
__global__ void prep_gates_k(const float* Wih, const float* Whh,
                             const float* b1, const float* b2,
                             u16* Wout, float* bsum, int KI, int K) {
  const int j = blockIdx.y;
  const int k = blockIdx.x * 256 + threadIdx.x;
  const int worig = (j & 3) * H_ + (j >> 2);
  const float v = (k < KI) ? Wih[worig * KI + k] : Whh[worig * H_ + (k - KI)];
  Wout[(long)j * K + k] = f2b(v);
  if (k == 0) bsum[j] = b1[worig] + b2[worig];
}

__global__ void cast_k(const float* s, u16* d) {
  const int i = blockIdx.x * 256 + threadIdx.x;
  d[i] = f2b(s[i]);
}

__global__ void init_k(u16* a, u16* b, unsigned* bar) {
  const int i = blockIdx.x * 256 + threadIdx.x;
  a[i] = 0; b[i] = 0;
  if (i < 1024) bar[i] = 0u;
}

__global__ void cast_feat_k(const int* f, float* o) {
  const int i = blockIdx.x * 256 + threadIdx.x;
  o[i] = b2f(f2b((float)f[i]));
}

__global__ void ln_k(const u16* hf, const u16* hb,
                     const float* g0, const float* b0,
                     const float* g1, const float* b1,
                     u16* A0, u16* A1) {
  const int b = blockIdx.x, t = threadIdx.x;
  const int k4 = t * 4;
  const u16* src = (k4 < H_) ? (hf + b * H_ + k4) : (hb + b * H_ + (k4 - H_));
  const ushort4 raw = *(const ushort4*)src;
  const float x0 = b2f(raw.x), x1 = b2f(raw.y), x2 = b2f(raw.z), x3 = b2f(raw.w);
  float s = x0 + x1 + x2 + x3;
  float sq = x0 * x0 + x1 * x1 + x2 * x2 + x3 * x3;
#pragma unroll
  for (int off = 32; off; off >>= 1) {
    s += __shfl_down(s, off);
    sq += __shfl_down(sq, off);
  }
  __shared__ float ss[4], ssq[4], smv[2];
  if ((t & 63) == 0) { ss[t >> 6] = s; ssq[t >> 6] = sq; }
  __syncthreads();
  if (t == 0) {
    const float S = ss[0] + ss[1] + ss[2] + ss[3];
    const float SQ = ssq[0] + ssq[1] + ssq[2] + ssq[3];
    const float m = S * (1.f / 1024.f);
    const float var = SQ * (1.f / 1024.f) - m * m;
    smv[0] = m; smv[1] = rsqrtf(var + 1e-5f);
  }
  __syncthreads();
  const float m = smv[0], rs = smv[1];
  const float4 ga = *(const float4*)(g0 + k4), ba = *(const float4*)(b0 + k4);
  const float4 gb = *(const float4*)(g1 + k4), bb = *(const float4*)(b1 + k4);
  ushort4 o0, o1;
  o0.x = f2b((x0 - m) * rs * ga.x + ba.x);
  o0.y = f2b((x1 - m) * rs * ga.y + ba.y);
  o0.z = f2b((x2 - m) * rs * ga.z + ba.z);
  o0.w = f2b((x3 - m) * rs * ga.w + ba.w);
  o1.x = f2b((x0 - m) * rs * gb.x + bb.x);
  o1.y = f2b((x1 - m) * rs * gb.y + bb.y);
  o1.z = f2b((x2 - m) * rs * gb.z + bb.z);
  o1.w = f2b((x3 - m) * rs * gb.w + bb.w);
  *(ushort4*)(A0 + b * 1024 + k4) = o0;
  *(ushort4*)(A1 + b * 1024 + k4) = o1;
}

__global__ void z_k(const float* mu, const float* lv, const float* eps,
                    u16* dz, float* dc) {
  const int i = blockIdx.x * 256 + threadIdx.x;
  const float z = mu[i] + __expf(0.5f * lv[i]) * eps[i];
  dz[i] = f2b(z);
  dc[(i & (H_ - 1)) * B_ + (i >> 9)] = z;   // c transposed [H][B]
}

extern "C" void kernel_launch(void* const* d_in, const int* in_sizes, int n_in,
                              void* d_out, int out_size, void* d_ws, size_t ws_size,
                              hipStream_t stream) {
  const int*   features = (const int*)d_in[0];
  const float* eps      = (const float*)d_in[1];
  const float* emb      = (const float*)d_in[2];
  const float* eWih_f   = (const float*)d_in[3];
  const float* eWhh_f   = (const float*)d_in[4];
  const float* ebih_f   = (const float*)d_in[5];
  const float* ebhh_f   = (const float*)d_in[6];
  const float* eWih_b   = (const float*)d_in[7];
  const float* eWhh_b   = (const float*)d_in[8];
  const float* ebih_b   = (const float*)d_in[9];
  const float* ebhh_b   = (const float*)d_in[10];
  const float* dWhh     = (const float*)d_in[12];
  const float* dbih     = (const float*)d_in[13];
  const float* dbhh     = (const float*)d_in[14];
  const float* mu_ln_g  = (const float*)d_in[15];
  const float* mu_ln_b  = (const float*)d_in[16];
  const float* mu_W     = (const float*)d_in[17];
  const float* mu_b     = (const float*)d_in[18];
  const float* lv_ln_g  = (const float*)d_in[19];
  const float* lv_ln_b  = (const float*)d_in[20];
  const float* lv_W     = (const float*)d_in[21];
  const float* lv_b     = (const float*)d_in[22];
  const float* ff_W     = (const float*)d_in[23];
  const float* ff_b     = (const float*)d_in[24];

  float* of = (float*)d_out;
  float* o_feat = of;
  float* o_fh   = of + (B_ * L_);
  float* o_mu   = o_fh + (long)B_ * DEC_T_ * V_;
  float* o_lv   = o_mu + (long)B_ * H_;

  // ---- ws layout (~25.9 MB, verified R5-R10) -------------------------------
  u16* hfa = (u16*)d_ws;
  u16* hba = hfa + NA_;
  u16* hfb = hba + NA_;
  u16* hbb = hfb + NA_;
  u16* Wenc_f = hbb + NA_;                  // 2048*768
  u16* Wenc_b = Wenc_f + 2048 * 768;        // 2048*768
  u16* Wdec   = Wenc_b + 2048 * 768;        // 2048*512
  u16* Wff    = Wdec + 2048 * 512;          // 1024*512
  u16* Wmu    = Wff + 1024 * 512;           // 512*1024
  u16* Wlv    = Wmu + 512 * 1024;           // 512*1024
  u16* embb   = Wlv + 512 * 1024;           // 1024*256
  float* bsum_f = (float*)(embb + V_ * E_);
  float* bsum_b = bsum_f + 2048;
  float* bsum_d = bsum_b + 2048;
  unsigned* bar = (unsigned*)(bsum_d + 2048);  // 1024 uints
  u16* dz     = (u16*)(bar + 1024);
  float* dc   = (float*)(dz + NA_);
  u16* An0    = hfb;                        // alias (dead post-enc)
  u16* An1    = Wenc_f;                     // alias (dead post-enc)
  u16* dech   = hfa;                        // alias: 7*NA over hfa..Wenc_b

  cast_feat_k<<<dim3(B_ * L_ / 256), dim3(256), 0, stream>>>(features, o_feat);
  init_k<<<dim3(NA_ / 256), dim3(256), 0, stream>>>(hfa, hba, bar);

  prep_gates_k<<<dim3(3, 2048), dim3(256), 0, stream>>>(eWih_f, eWhh_f, ebih_f, ebhh_f, Wenc_f, bsum_f, E_, E_ + H_);
  prep_gates_k<<<dim3(3, 2048), dim3(256), 0, stream>>>(eWih_b, eWhh_b, ebih_b, ebhh_b, Wenc_b, bsum_b, E_, E_ + H_);
  prep_gates_k<<<dim3(2, 2048), dim3(256), 0, stream>>>(nullptr, dWhh, dbih, dbhh, Wdec, bsum_d, 0, H_);
  cast_k<<<dim3(1024 * 512 / 256), dim3(256), 0, stream>>>(ff_W, Wff);
  cast_k<<<dim3(512 * 1024 / 256), dim3(256), 0, stream>>>(mu_W, Wmu);
  cast_k<<<dim3(512 * 1024 / 256), dim3(256), 0, stream>>>(lv_W, Wlv);
  cast_k<<<dim3(V_ * E_ / 256), dim3(256), 0, stream>>>(emb, embb);

  // ---- encoder: ONE persistent launch, barrier-free K-loop -----------------
  enc_persist_k<<<dim3(256), dim3(512), 0, stream>>>(
      features, embb, Wenc_f, Wenc_b, bsum_f, bsum_b,
      hfa, hfb, hba, hbb, bar);
  // L=32 even -> final fwd h in hfa, bwd h in hba.

  // ---- LN + mu/lv heads ----------------------------------------------------
  ln_k<<<dim3(B_), dim3(256), 0, stream>>>(hfa, hba, mu_ln_g, mu_ln_b, lv_ln_g, lv_ln_b, An0, An1);
  {
    OP pm{}, pl{};
    pm.A = An0; pm.W = Wmu; pm.bias = mu_b; pm.Cf = o_mu; pm.ldc = H_; pm.K = 2 * H_;
    pl = pm;
    pl.A = An1; pl.W = Wlv; pl.bias = lv_b; pl.Cf = o_lv;
    out_mfma_k<<<dim3(4, 16, 2), dim3(256), 0, stream>>>(pm, pl);
  }
  z_k<<<dim3(NA_ / 256), dim3(256), 0, stream>>>(o_mu, o_lv, eps, dz, dc);

  // ---- decoder: ONE persistent launch, barrier-free K-loop -----------------
  dec_persist_k<<<dim3(256), dim3(512), 0, stream>>>(Wdec, bsum_d, dz, dc, dech, bar);

  // ---- ONE batched ff GEMM over all 7 steps --------------------------------
  {
    OP po{};
    po.A = dech; po.W = Wff; po.bias = ff_b;
    po.Cf = o_fh; po.ldc = 0;
    po.K = H_;
    out_mfma_k<<<dim3(8, DEC_T_ * 16, 1), dim3(256), 0, stream>>>(po, po);
  }
}